// Round 2
// baseline (333.604 us; speedup 1.0000x reference)
//
#include <hip/hip_runtime.h>
#include <cstdint>
#include <cstddef>

#define H_CH 1024
#define NST  64
#define OUTF 512
#define LSEQ 4096
#define TCH  512          // timesteps per chunk
#define NCHK 8            // LSEQ / TCH

typedef __bf16 bf16x8 __attribute__((ext_vector_type(8)));
typedef float floatx4 __attribute__((ext_vector_type(4)));

__device__ __forceinline__ unsigned short f2bf(float f) {
    __bf16 b = (__bf16)f;
    return __builtin_bit_cast(unsigned short, b);
}

// per-channel discretization (fp64 for phase accuracy over 4096 steps)
__device__ __forceinline__ void lam_of(int c, int lane,
    const float* log_dt, const float* A_re, const float* A_im,
    float& lam_re, float& lam_im, double& dar, double& dai)
{
    const int idx = c * NST + lane;
    double are = (double)A_re[idx];
    double aim = (double)A_im[idx];
    double dt  = exp((double)log_dt[c]);
    dar = dt * are; dai = dt * aim;
    double er  = exp(dar);
    lam_re = (float)(er * cos(dai));
    lam_im = (float)(er * sin(dai));
}

__device__ __forceinline__ float posenc_of(int c, int l, float freq, int axis, int is_cos)
{
    int pos;
    if (axis == 0)      pos = l >> 8;
    else if (axis == 1) pos = (l >> 4) & 15;
    else                pos = l & 15;
    const float arg = (float)pos * freq;
    return is_cos ? cosf(arg) : sinf(arg);
}

// ---------------------------------------------------------------------------
// Pass 1: per-chunk end-states with zero init.  One wave per (b,c,chunk).
// ---------------------------------------------------------------------------
__global__ __launch_bounds__(256) void s4_pass1_kernel(
    const float* __restrict__ x, const float* __restrict__ log_dt,
    const float* __restrict__ A_re, const float* __restrict__ A_im,
    float* __restrict__ states)             // [b*c][NCHK][64] float2
{
    const int wv   = threadIdx.x >> 6;
    const int lane = threadIdx.x & 63;
    const int gw   = blockIdx.x * 4 + wv;   // 0..16383
    const int chunk = gw & (NCHK - 1);
    const int wid   = gw >> 3;              // b*1024 + c
    const int c     = wid & 1023;

    float lam_re, lam_im; double dar, dai;
    lam_of(c, lane, log_dt, A_re, A_im, lam_re, lam_im, dar, dai);

    const int axis   = (c >= 684) ? 2 : ((c >= 342) ? 1 : 0);
    const int j      = c - 342 * axis;
    const float freq = (float)exp(-log(10000.0) * (double)(2 * (j >> 1)) / 342.0);
    const int is_cos = j & 1;

    const float* xp = x + (size_t)wid * LSEQ + chunk * TCH;
    float s_re = 0.f, s_im = 0.f;

    for (int sc = 0; sc < TCH / 64; ++sc) {
        const int l  = chunk * TCH + sc * 64 + lane;
        const float pe = posenc_of(c, l, freq, axis, is_cos);
        const float vv = xp[sc * 64 + lane] + pe;
        #pragma unroll
        for (int t = 0; t < 64; ++t) {
            float vt = __int_as_float(__builtin_amdgcn_readlane(__float_as_int(vv), t));
            float tre = fmaf(lam_re, s_re, fmaf(-lam_im, s_im, vt));
            float tim = fmaf(lam_re, s_im, lam_im * s_re);
            s_re = tre; s_im = tim;
        }
    }
    float2* st = (float2*)states + ((size_t)wid * NCHK + chunk) * 64 + lane;
    *st = make_float2(s_re, s_im);
}

// ---------------------------------------------------------------------------
// Pass 2: exclusive scan over chunks, in place.  One wave per (b,c).
// ---------------------------------------------------------------------------
__global__ __launch_bounds__(256) void s4_pass2_kernel(
    const float* __restrict__ log_dt, const float* __restrict__ A_re,
    const float* __restrict__ A_im, float* __restrict__ states)
{
    const int wv   = threadIdx.x >> 6;
    const int lane = threadIdx.x & 63;
    const int wid  = blockIdx.x * 4 + wv;   // 0..2047
    const int c    = wid & 1023;

    float lam_re, lam_im; double dar, dai;
    lam_of(c, lane, log_dt, A_re, A_im, lam_re, lam_im, dar, dai);
    // lambda^TCH computed exactly from dt*A (no power accumulation)
    double er = exp(dar * (double)TCH);
    const float lTre = (float)(er * cos(dai * (double)TCH));
    const float lTim = (float)(er * sin(dai * (double)TCH));

    float2* st = (float2*)states + (size_t)wid * NCHK * 64 + lane;
    float cr = 0.f, ci = 0.f;
    #pragma unroll
    for (int jc = 0; jc < NCHK; ++jc) {
        float2 e = st[jc * 64];
        st[jc * 64] = make_float2(cr, ci);          // exclusive prefix
        float nr = fmaf(lTre, cr, fmaf(-lTim, ci, e.x));
        float ni = fmaf(lTre, ci, fmaf(lTim, cr, e.y));
        cr = nr; ci = ni;
    }
}

// ---------------------------------------------------------------------------
// Pass 3: outputs.  One wave per (b,c,chunk), init state from pass 2.
// ---------------------------------------------------------------------------
__global__ __launch_bounds__(256) void s4_pass3_kernel(
    const float* __restrict__ x, const float* __restrict__ log_dt,
    const float* __restrict__ A_re, const float* __restrict__ A_im,
    const float* __restrict__ C_re, const float* __restrict__ C_im,
    const float* __restrict__ Dp, const float* __restrict__ states,
    unsigned short* __restrict__ g_bcl)
{
    __shared__ __align__(16) float pbuf[4][64 * 68];   // [t][n], stride 68
    const int wv   = threadIdx.x >> 6;
    const int lane = threadIdx.x & 63;
    const int gw   = blockIdx.x * 4 + wv;
    const int chunk = gw & (NCHK - 1);
    const int wid   = gw >> 3;
    const int c     = wid & 1023;

    float lam_re, lam_im; double dar, dai;
    lam_of(c, lane, log_dt, A_re, A_im, lam_re, lam_im, dar, dai);

    // Ct = C*(lambda-1)/A, fold 2*Re(.) into real coefficients
    {
        // recompute lambda in double for the coefficient math
    }
    const int idx = c * NST + lane;
    double are = (double)A_re[idx], aim = (double)A_im[idx];
    double cre = (double)C_re[idx], cim = (double)C_im[idx];
    double er  = exp(dar);
    double lre = er * cos(dai), lim = er * sin(dai);
    double nre = lre - 1.0, nim = lim;
    double d2  = are * are + aim * aim;
    double qre = (nre * are + nim * aim) / d2;
    double qim = (nim * are - nre * aim) / d2;
    const float c2r  = (float)( 2.0 * (cre * qre - cim * qim));
    const float c2mi = (float)(-2.0 * (cre * qim + cim * qre));
    const float Dc   = Dp[c];

    const int axis   = (c >= 684) ? 2 : ((c >= 342) ? 1 : 0);
    const int j      = c - 342 * axis;
    const float freq = (float)exp(-log(10000.0) * (double)(2 * (j >> 1)) / 342.0);
    const int is_cos = j & 1;

    const float* xp = x + (size_t)wid * LSEQ + chunk * TCH;
    unsigned short* gp = g_bcl + (size_t)wid * LSEQ + chunk * TCH;
    float* pw = &pbuf[wv][0];

    const float2 s0 = ((const float2*)states)[((size_t)wid * NCHK + chunk) * 64 + lane];
    float s_re = s0.x, s_im = s0.y;

    for (int sc = 0; sc < TCH / 64; ++sc) {
        const int l  = chunk * TCH + sc * 64 + lane;
        const float pe = posenc_of(c, l, freq, axis, is_cos);
        const float vv = xp[sc * 64 + lane] + pe;

        #pragma unroll
        for (int t = 0; t < 64; ++t) {
            float vt = __int_as_float(__builtin_amdgcn_readlane(__float_as_int(vv), t));
            float tre = fmaf(lam_re, s_re, fmaf(-lam_im, s_im, vt));
            float tim = fmaf(lam_re, s_im, lam_im * s_re);
            s_re = tre; s_im = tim;
            pw[t * 68 + lane] = fmaf(c2r, s_re, c2mi * s_im);   // row t, 2-way free
        }
        // lane l sums row l (contiguous, 16B-aligned via stride 68)
        const floatx4* row = (const floatx4*)(pw + lane * 68);
        floatx4 r0 = {0.f,0.f,0.f,0.f}, r1 = r0, r2 = r0, r3 = r0;
        #pragma unroll
        for (int q = 0; q < 4; ++q) {
            r0 += row[q]; r1 += row[q + 4]; r2 += row[q + 8]; r3 += row[q + 12];
        }
        floatx4 rs = (r0 + r1) + (r2 + r3);
        float acc = (rs.x + rs.y) + (rs.z + rs.w);

        float y = fmaf(Dc, vv, acc);
        float u = y + 0.044715f * y * y * y;
        float g = 0.5f * y * (1.f + tanhf(0.7978845608028654f * u));
        gp[sc * 64 + lane] = f2bf(g);
    }
}

// ---------------------------------------------------------------------------
// Transpose g (b,c,l) bf16 -> gT (b,l,c) bf16, 64x64 LDS tiles.
// ---------------------------------------------------------------------------
__global__ __launch_bounds__(256) void transpose_g_kernel(
    const unsigned short* __restrict__ g_bcl, unsigned short* __restrict__ gT)
{
    __shared__ unsigned int tileU[64 * 33];
    const int t  = threadIdx.x;
    const int ty = t >> 5;
    const int tx = t & 31;
    const int l0 = blockIdx.x * 64;
    const int c0 = blockIdx.y * 64;
    const int b  = blockIdx.z;

    #pragma unroll
    for (int r = 0; r < 8; ++r) {
        const int ci = r * 8 + ty;
        tileU[ci * 33 + tx] =
            *(const unsigned int*)&g_bcl[((size_t)b * H_CH + c0 + ci) * LSEQ + l0 + tx * 2];
    }
    __syncthreads();
    #pragma unroll
    for (int r = 0; r < 8; ++r) {
        const int li = r * 8 + ty;
        unsigned int ua = tileU[(2 * tx)     * 33 + (li >> 1)];
        unsigned int ub = tileU[(2 * tx + 1) * 33 + (li >> 1)];
        unsigned int s0 = (li & 1) ? (ua >> 16) : (ua & 0xffffu);
        unsigned int s1 = (li & 1) ? (ub >> 16) : (ub & 0xffffu);
        *(unsigned int*)&gT[((size_t)b * LSEQ + l0 + li) * H_CH + c0 + 2 * tx] =
            s0 | (s1 << 16);
    }
}

// ---------------------------------------------------------------------------
// W (k=1024, o=512) fp32 -> Wt (o=512, k=1024) bf16.
// ---------------------------------------------------------------------------
__global__ __launch_bounds__(256) void transpose_w_kernel(
    const float* __restrict__ W, unsigned short* __restrict__ Wt)
{
    __shared__ float tileF[64 * 65];
    const int t  = threadIdx.x;
    const int o0 = blockIdx.x * 64;
    const int k0 = blockIdx.y * 64;
    {
        const int ty = t >> 6, tx = t & 63;
        #pragma unroll
        for (int r = 0; r < 16; ++r) {
            const int ki = r * 4 + ty;
            tileF[ki * 65 + tx] = W[(size_t)(k0 + ki) * OUTF + o0 + tx];
        }
    }
    __syncthreads();
    {
        const int ty = t >> 5, tx = t & 31;
        #pragma unroll
        for (int r = 0; r < 8; ++r) {
            const int oi = r * 8 + ty;
            unsigned int u0 = f2bf(tileF[(2 * tx)     * 65 + oi]);
            unsigned int u1 = f2bf(tileF[(2 * tx + 1) * 65 + oi]);
            *(unsigned int*)&Wt[(size_t)(o0 + oi) * H_CH + k0 + 2 * tx] = u0 | (u1 << 16);
        }
    }
}

// ---------------------------------------------------------------------------
// GEMM: out[b,o,l] = sum_k Wt[o,k]*gT[b,l,k] + b_out[o].
// 64(o) x 128(l) tiles, BK=32, 512 blocks (2/CU).  Wave w: 64o x 32l.
// ---------------------------------------------------------------------------
__global__ __launch_bounds__(256) void gemm_kernel(
    const unsigned short* __restrict__ gT, const unsigned short* __restrict__ Wt,
    const float* __restrict__ b_out, float* __restrict__ out)
{
    __shared__ unsigned short As[64 * 40];      // [o][k] rows padded to 80B
    __shared__ unsigned short Bs[128 * 40];     // [l][k]

    const int t    = threadIdx.x;
    const int lane = t & 63;
    const int w    = t >> 6;                    // wave id: l-quarter
    const int lm   = lane & 15;
    const int lq   = lane >> 4;

    const int l0 = blockIdx.x * 128;
    const int o0 = blockIdx.y * 64;
    const int bb = blockIdx.z;
    const unsigned short* gB = gT + (size_t)bb * LSEQ * H_CH;

    floatx4 acc[4][2];
    #pragma unroll
    for (int i = 0; i < 4; ++i)
        #pragma unroll
        for (int jj = 0; jj < 2; ++jj)
            acc[i][jj] = (floatx4){0.f, 0.f, 0.f, 0.f};

    for (int kt = 0; kt < 32; ++kt) {
        const int k0 = kt * 32;
        __syncthreads();
        {   // A: 64x32 = one uint4 per thread
            const int row = t >> 2, q = t & 3;
            *(uint4*)&As[row * 40 + q * 8] =
                *(const uint4*)(Wt + (size_t)(o0 + row) * H_CH + k0 + q * 8);
        }
        #pragma unroll
        for (int half = 0; half < 2; ++half) {  // B: 128x32 = two uint4
            const int chunk = t + half * 256;
            const int row = chunk >> 2, q = chunk & 3;
            *(uint4*)&Bs[row * 40 + q * 8] =
                *(const uint4*)(gB + (size_t)(l0 + row) * H_CH + k0 + q * 8);
        }
        __syncthreads();

        bf16x8 af[4], bfr[2];
        #pragma unroll
        for (int sm = 0; sm < 4; ++sm)
            af[sm] = *(const bf16x8*)&As[(sm * 16 + lm) * 40 + lq * 8];
        #pragma unroll
        for (int sn = 0; sn < 2; ++sn)
            bfr[sn] = *(const bf16x8*)&Bs[(w * 32 + sn * 16 + lm) * 40 + lq * 8];

        #pragma unroll
        for (int sm = 0; sm < 4; ++sm)
            #pragma unroll
            for (int sn = 0; sn < 2; ++sn)
                acc[sm][sn] = __builtin_amdgcn_mfma_f32_16x16x32_bf16(
                    af[sm], bfr[sn], acc[sm][sn], 0, 0, 0);
    }

    #pragma unroll
    for (int sm = 0; sm < 4; ++sm)
        #pragma unroll
        for (int sn = 0; sn < 2; ++sn)
            #pragma unroll
            for (int r = 0; r < 4; ++r) {
                const int o = o0 + sm * 16 + lq * 4 + r;            // D row = o
                const int l = l0 + w * 32 + sn * 16 + lm;           // D col = l
                out[((size_t)bb * OUTF + o) * LSEQ + l] = acc[sm][sn][r] + b_out[o];
            }
}

// ---------------------------------------------------------------------------
extern "C" void kernel_launch(void* const* d_in, const int* in_sizes, int n_in,
                              void* d_out, int out_size, void* d_ws, size_t ws_size,
                              hipStream_t stream) {
    const float* x      = (const float*)d_in[0];
    const float* log_dt = (const float*)d_in[1];
    const float* A_re   = (const float*)d_in[2];
    const float* A_im   = (const float*)d_in[3];
    const float* C_re   = (const float*)d_in[4];
    const float* C_im   = (const float*)d_in[5];
    const float* Dp     = (const float*)d_in[6];
    const float* W_out  = (const float*)d_in[7];
    const float* b_out  = (const float*)d_in[8];
    float* out = (float*)d_out;

    // Workspace overlay (32 MiB total):
    //   [0,16M)   g_bcl (pass3 -> transpose_g), then Wt reuses [0,1M)
    //   [16M,24.4M) states (pass1..pass3), then gT reuses [16M,32M)
    char* ws = (char*)d_ws;
    unsigned short* g_bcl = (unsigned short*)ws;
    float*          states = (float*)(ws + (size_t)16 * 1024 * 1024);
    unsigned short* gT     = (unsigned short*)(ws + (size_t)16 * 1024 * 1024);
    unsigned short* Wt     = (unsigned short*)ws;

    s4_pass1_kernel<<<4096, 256, 0, stream>>>(x, log_dt, A_re, A_im, states);
    s4_pass2_kernel<<<512, 256, 0, stream>>>(log_dt, A_re, A_im, states);
    s4_pass3_kernel<<<4096, 256, 0, stream>>>(x, log_dt, A_re, A_im, C_re, C_im,
                                              Dp, states, g_bcl);
    transpose_g_kernel<<<dim3(64, 16, 2), 256, 0, stream>>>(g_bcl, gT);
    transpose_w_kernel<<<dim3(8, 16), 256, 0, stream>>>(W_out, Wt);
    gemm_kernel<<<dim3(32, 8, 2), 256, 0, stream>>>(gT, Wt, b_out, out);
}

// Round 3
// 182.778 us; speedup vs baseline: 1.8252x; 1.8252x over previous
//
#include <hip/hip_runtime.h>
#include <cstdint>
#include <cstddef>

#define H_CH 1024
#define OUTF 512
#define LSEQ 4096

typedef __bf16 bf16x8 __attribute__((ext_vector_type(8)));
typedef float floatx4 __attribute__((ext_vector_type(4)));

__device__ __forceinline__ unsigned short f2bf(float f) {
    __bf16 b = (__bf16)f;
    return __builtin_bit_cast(unsigned short, b);
}
__device__ __forceinline__ unsigned int pack2(float a, float b) {
    return (unsigned int)f2bf(a) | ((unsigned int)f2bf(b) << 16);
}
__device__ __forceinline__ float bf2f(unsigned short u) {
    unsigned int x = ((unsigned int)u) << 16;
    return __builtin_bit_cast(float, x);
}
struct c32 { float x, y; };
__device__ __forceinline__ c32 cmul(c32 a, c32 b) {
    return { fmaf(a.x, b.x, -a.y * b.y), fmaf(a.x, b.y, a.y * b.x) };
}
__device__ __forceinline__ c32 cpow16(c32 a, int w) {   // a^(16*w), w in 0..3
    c32 p = {1.f, 0.f};
    if (w) {
        c32 a2 = cmul(a, a), a4 = cmul(a2, a2), a8 = cmul(a4, a4), a16 = cmul(a8, a8);
        p = a16;
        for (int k = 1; k < w; ++k) p = cmul(p, a16);
    }
    return p;
}

// ---------------------------------------------------------------------------
// prep_v: v[b,c,l] = bf16(x + posenc).  Posenc per channel has only 16 values.
// ---------------------------------------------------------------------------
__global__ __launch_bounds__(256) void prep_v_kernel(
    const float* __restrict__ x, unsigned short* __restrict__ v)
{
    __shared__ float pe16[16];
    const int wid = blockIdx.x;           // b*1024+c
    const int c = wid & (H_CH - 1);
    const int t = threadIdx.x;
    const int axis = (c >= 684) ? 2 : ((c >= 342) ? 1 : 0);
    const int j = c - 342 * axis;
    const float freq = (float)exp(-log(10000.0) * (double)(2 * (j >> 1)) / 342.0);
    const int is_cos = j & 1;
    if (t < 16) { float a = (float)t * freq; pe16[t] = is_cos ? cosf(a) : sinf(a); }
    __syncthreads();
    const float* xp = x + (size_t)wid * LSEQ;
    unsigned int* vp = (unsigned int*)(v + (size_t)wid * LSEQ);
    #pragma unroll
    for (int r = 0; r < 2; ++r) {
        const int i = r * 256 + t, l0 = i * 8;
        float4 f0 = *(const float4*)(xp + l0);
        float4 f1 = *(const float4*)(xp + l0 + 4);
        float e[8] = {f0.x, f0.y, f0.z, f0.w, f1.x, f1.y, f1.z, f1.w};
        unsigned int o[4];
        #pragma unroll
        for (int k = 0; k < 4; ++k) {
            const int la = l0 + 2 * k, lb = la + 1;
            const int pa = axis == 0 ? (la >> 8) : axis == 1 ? ((la >> 4) & 15) : (la & 15);
            const int pb = axis == 0 ? (lb >> 8) : axis == 1 ? ((lb >> 4) & 15) : (lb & 15);
            o[k] = pack2(e[2 * k] + pe16[pa], e[2 * k + 1] + pe16[pb]);
        }
        *(uint4*)&vp[i * 4] = make_uint4(o[0], o[1], o[2], o[3]);
    }
}

// ---------------------------------------------------------------------------
// coef: per (c,n) fp64-exact {lam, inv=lam^-1, lamQ=lam^64, 2*conj-folded Ct}.
// ---------------------------------------------------------------------------
__global__ __launch_bounds__(256) void coef_kernel(
    const float* __restrict__ log_dt, const float* __restrict__ A_re,
    const float* __restrict__ A_im, const float* __restrict__ C_re,
    const float* __restrict__ C_im, float* __restrict__ coef)
{
    const int i = blockIdx.x * 256 + threadIdx.x;   // c*64+n
    const int c = i >> 6;
    double are = A_re[i], aim = A_im[i], cre = C_re[i], cim = C_im[i];
    double dt  = exp((double)log_dt[c]);
    double dar = dt * are, dai = dt * aim;
    double er = exp(dar), cd = cos(dai), sd = sin(dai);
    double lre = er * cd, limm = er * sd;
    double ei = exp(-dar);
    double eQ = exp(64.0 * dar), cQ = cos(64.0 * dai), sQ = sin(64.0 * dai);
    double nre = lre - 1.0, nim = limm;
    double d2  = are * are + aim * aim;
    double qre = (nre * are + nim * aim) / d2;
    double qim = (nim * are - nre * aim) / d2;
    double ctre = cre * qre - cim * qim, ctim = cre * qim + cim * qre;
    float4 w0 = make_float4((float)lre, (float)limm, (float)(ei * cd), (float)(-ei * sd));
    float4 w1 = make_float4((float)(eQ * cQ), (float)(eQ * sQ),
                            (float)(2.0 * ctre), (float)(-2.0 * ctim));
    *(float4*)&coef[(size_t)i * 8]     = w0;
    *(float4*)&coef[(size_t)i * 8 + 4] = w1;
}

// ---------------------------------------------------------------------------
// chunk_delta: Delta = F @ V per (b,c).  F[2n..2n+1][u] = (Re,Im) lam^(63-u).
// Output S[wid][chunk][128] bf16 (comp-interleaved).
// ---------------------------------------------------------------------------
__global__ __launch_bounds__(256) void chunk_delta_kernel(
    const unsigned short* __restrict__ v, const float* __restrict__ coef,
    unsigned short* __restrict__ S)
{
    __shared__ __align__(16) unsigned short Fs[128 * 72];
    __shared__ __align__(16) unsigned short Vs[64 * 72];
    const int wid = blockIdx.x;
    const int c = wid & (H_CH - 1);
    const int t = threadIdx.x, lane = t & 63, w = t >> 6, n = lane;
    const int lm = lane & 15, lq = lane >> 4;

    uint4 vreg[2];
    #pragma unroll
    for (int h = 0; h < 2; ++h) {
        const int idx = t + 256 * h, row = idx >> 3, q = idx & 7;
        vreg[h] = *(const uint4*)(v + (size_t)wid * LSEQ + row * 64 + q * 8);
    }
    const float* cf = coef + ((size_t)c * 64 + n) * 8;
    c32 lam = {cf[0], cf[1]}, inv = {cf[2], cf[3]};
    // z = lam^63 * inv^(16w) = lam^(63-16w)
    c32 l2 = cmul(lam, lam), l4 = cmul(l2, l2), l8 = cmul(l4, l4);
    c32 l16 = cmul(l8, l8), l32 = cmul(l16, l16);
    c32 z = cmul(cmul(cmul(cmul(cmul(l32, l16), l8), l4), l2), lam);
    z = cmul(z, cpow16(inv, w));
    #pragma unroll
    for (int h = 0; h < 2; ++h) {
        const int idx = t + 256 * h, row = idx >> 3, q = idx & 7;
        *(uint4*)&Vs[row * 72 + q * 8] = vreg[h];
    }
    #pragma unroll
    for (int s = 0; s < 16; ++s) {
        const int u = 16 * w + s;
        Fs[(2 * n) * 72 + u]     = f2bf(z.x);
        Fs[(2 * n + 1) * 72 + u] = f2bf(z.y);
        z = cmul(z, inv);
    }
    __syncthreads();

    floatx4 acc[2][4];
    #pragma unroll
    for (int a = 0; a < 2; ++a)
        #pragma unroll
        for (int b = 0; b < 4; ++b) acc[a][b] = (floatx4){0.f, 0.f, 0.f, 0.f};
    #pragma unroll
    for (int kt = 0; kt < 2; ++kt) {
        bf16x8 a0 = *(const bf16x8*)&Fs[(32 * w + lm) * 72 + kt * 32 + lq * 8];
        bf16x8 a1 = *(const bf16x8*)&Fs[(32 * w + 16 + lm) * 72 + kt * 32 + lq * 8];
        #pragma unroll
        for (int nt = 0; nt < 4; ++nt) {
            bf16x8 b = *(const bf16x8*)&Vs[(nt * 16 + lm) * 72 + kt * 32 + lq * 8];
            acc[0][nt] = __builtin_amdgcn_mfma_f32_16x16x32_bf16(a0, b, acc[0][nt], 0, 0, 0);
            acc[1][nt] = __builtin_amdgcn_mfma_f32_16x16x32_bf16(a1, b, acc[1][nt], 0, 0, 0);
        }
    }
    unsigned short* Sp = S + (size_t)wid * 8192;
    #pragma unroll
    for (int sm = 0; sm < 2; ++sm)
        #pragma unroll
        for (int nt = 0; nt < 4; ++nt) {
            const int row = 32 * w + sm * 16 + lq * 4, col = nt * 16 + lm;
            uint2 u2 = make_uint2(pack2(acc[sm][nt][0], acc[sm][nt][1]),
                                  pack2(acc[sm][nt][2], acc[sm][nt][3]));
            *(uint2*)(Sp + col * 128 + row) = u2;
        }
}

// ---------------------------------------------------------------------------
// scan: in-place exclusive chunk-scan of S.  One wave per (b,c), lane=state.
// ---------------------------------------------------------------------------
__global__ __launch_bounds__(256) void scan_kernel(
    const float* __restrict__ coef, unsigned short* __restrict__ S)
{
    const int wv = threadIdx.x >> 6, lane = threadIdx.x & 63;
    const int wid = blockIdx.x * 4 + wv;
    const int c = wid & (H_CH - 1);
    const float* cf = coef + ((size_t)c * 64 + lane) * 8;
    const float lQr = cf[4], lQi = cf[5];
    unsigned int* Sp = (unsigned int*)(S + (size_t)wid * 8192);
    float sr = 0.f, si = 0.f;
    for (int jo = 0; jo < 8; ++jo) {
        unsigned int in[8], out[8];
        #pragma unroll
        for (int ji = 0; ji < 8; ++ji) in[ji] = Sp[(jo * 8 + ji) * 64 + lane];
        #pragma unroll
        for (int ji = 0; ji < 8; ++ji) {
            out[ji] = pack2(sr, si);
            float dr = bf2f((unsigned short)(in[ji] & 0xffff));
            float di = bf2f((unsigned short)(in[ji] >> 16));
            float nr = fmaf(lQr, sr, fmaf(-lQi, si, dr));
            float ni = fmaf(lQr, si, fmaf(lQi, sr, di));
            sr = nr; si = ni;
        }
        #pragma unroll
        for (int ji = 0; ji < 8; ++ji) Sp[(jo * 8 + ji) * 64 + lane] = out[ji];
    }
}

// ---------------------------------------------------------------------------
// intra_inter: Y = tril(P@R)@V + E@Shat, + D*v, gelu -> g[b,c,l] bf16.
// ---------------------------------------------------------------------------
__global__ __launch_bounds__(256) void intra_inter_kernel(
    const unsigned short* __restrict__ v, const float* __restrict__ coef,
    const unsigned short* __restrict__ S, const float* __restrict__ Dp,
    unsigned short* __restrict__ g)
{
    __shared__ __align__(16) unsigned short Ps[65 * 136];
    __shared__ __align__(16) unsigned char RY[64 * 136 * 2];  // Rs bf16 / ytile f32[64*68]
    __shared__ __align__(16) unsigned short Vs[64 * 72];
    __shared__ __align__(16) unsigned short Ss[64 * 136];
    __shared__ __align__(16) unsigned short Ts[64 * 72];
    unsigned short* Rs = (unsigned short*)RY;
    float* ytile = (float*)RY;

    const int wid = blockIdx.x;
    const int c = wid & (H_CH - 1);
    const int t = threadIdx.x, lane = t & 63, w = t >> 6, n = lane;
    const int lm = lane & 15, lq = lane >> 4;

    uint4 vreg[2], sreg[4];
    #pragma unroll
    for (int h = 0; h < 2; ++h) {
        const int idx = t + 256 * h, row = idx >> 3, q = idx & 7;
        vreg[h] = *(const uint4*)(v + (size_t)wid * LSEQ + row * 64 + q * 8);
    }
    #pragma unroll
    for (int h = 0; h < 4; ++h) {
        const int idx = t + 256 * h, row = idx >> 4, qq = idx & 15;
        sreg[h] = *(const uint4*)(S + (size_t)wid * 8192 + row * 128 + qq * 8);
    }
    const float* cf = coef + ((size_t)c * 64 + n) * 8;
    c32 lam = {cf[0], cf[1]}, inv = {cf[2], cf[3]};
    const float c2r = cf[6], c2mi = cf[7];
    const float Dc = Dp[c];

    #pragma unroll
    for (int h = 0; h < 2; ++h) {
        const int idx = t + 256 * h, row = idx >> 3, q = idx & 7;
        *(uint4*)&Vs[row * 72 + q * 8] = vreg[h];
    }
    #pragma unroll
    for (int h = 0; h < 4; ++h) {
        const int idx = t + 256 * h, row = idx >> 4, qq = idx & 15;
        *(uint4*)&Ss[row * 136 + qq * 8] = sreg[h];
    }
    // P rows t: (Re, -Im) of 2*Ct*lam^t ; wave w covers t in [16w,16w+16) (+row 64 on w=3)
    {
        c32 z = cmul((c32){c2r, -c2mi}, cpow16(lam, w));
        const int steps = (w == 3) ? 17 : 16;
        for (int s = 0; s < steps; ++s) {
            const int tt = 16 * w + s;
            *(unsigned int*)&Ps[tt * 136 + 2 * n] = pack2(z.x, -z.y);
            z = cmul(z, lam);
        }
    }
    // R rows u: (Re, Im) of lam^-u
    {
        c32 z = cpow16(inv, w);
        #pragma unroll
        for (int s = 0; s < 16; ++s) {
            const int u = 16 * w + s;
            *(unsigned int*)&Rs[u * 136 + 2 * n] = pack2(z.x, z.y);
            z = cmul(z, inv);
        }
    }
    __syncthreads();

    // GEMM1: T = tril(P @ R), M=N=64, K=128; wave w -> m-strip 16w.
    floatx4 a1[4];
    #pragma unroll
    for (int nt = 0; nt < 4; ++nt) a1[nt] = (floatx4){0.f, 0.f, 0.f, 0.f};
    #pragma unroll
    for (int kt = 0; kt < 4; ++kt) {
        bf16x8 a = *(const bf16x8*)&Ps[(16 * w + lm) * 136 + kt * 32 + lq * 8];
        #pragma unroll
        for (int nt = 0; nt < 4; ++nt) {
            bf16x8 b = *(const bf16x8*)&Rs[(nt * 16 + lm) * 136 + kt * 32 + lq * 8];
            a1[nt] = __builtin_amdgcn_mfma_f32_16x16x32_bf16(a, b, a1[nt], 0, 0, 0);
        }
    }
    #pragma unroll
    for (int nt = 0; nt < 4; ++nt)
        #pragma unroll
        for (int r = 0; r < 4; ++r) {
            const int row = 16 * w + lq * 4 + r, col = nt * 16 + lm;
            Ts[row * 72 + col] = f2bf(row >= col ? a1[nt][r] : 0.f);
        }
    __syncthreads();

    // GEMM2: Y = T@V + E@Shat  (E = P rows shifted by 1)
    floatx4 a2[4];
    #pragma unroll
    for (int nt = 0; nt < 4; ++nt) a2[nt] = (floatx4){0.f, 0.f, 0.f, 0.f};
    #pragma unroll
    for (int kt = 0; kt < 2; ++kt) {
        bf16x8 a = *(const bf16x8*)&Ts[(16 * w + lm) * 72 + kt * 32 + lq * 8];
        #pragma unroll
        for (int nt = 0; nt < 4; ++nt) {
            bf16x8 b = *(const bf16x8*)&Vs[(nt * 16 + lm) * 72 + kt * 32 + lq * 8];
            a2[nt] = __builtin_amdgcn_mfma_f32_16x16x32_bf16(a, b, a2[nt], 0, 0, 0);
        }
    }
    #pragma unroll
    for (int kt = 0; kt < 4; ++kt) {
        bf16x8 a = *(const bf16x8*)&Ps[(16 * w + lm + 1) * 136 + kt * 32 + lq * 8];
        #pragma unroll
        for (int nt = 0; nt < 4; ++nt) {
            bf16x8 b = *(const bf16x8*)&Ss[(nt * 16 + lm) * 136 + kt * 32 + lq * 8];
            a2[nt] = __builtin_amdgcn_mfma_f32_16x16x32_bf16(a, b, a2[nt], 0, 0, 0);
        }
    }
    // epilogue: skip + gelu -> ytile[chunk][t] (overlays Rs; Rs dead)
    #pragma unroll
    for (int nt = 0; nt < 4; ++nt)
        #pragma unroll
        for (int r = 0; r < 4; ++r) {
            const int tt = 16 * w + lq * 4 + r, chunk = nt * 16 + lm;
            const float vv = bf2f(Vs[chunk * 72 + tt]);
            const float y = fmaf(Dc, vv, a2[nt][r]);
            const float u = y + 0.044715f * y * y * y;
            const float gg = 0.5f * y * (1.f + tanhf(0.7978845608028654f * u));
            ytile[chunk * 68 + tt] = gg;
        }
    __syncthreads();
    unsigned int* gp = (unsigned int*)(g + (size_t)wid * LSEQ);
    #pragma unroll
    for (int q = 0; q < 8; ++q) {
        const int idx = q * 256 + t, l = idx * 2;
        const int ch = l >> 6, tt = l & 63;
        gp[idx] = pack2(ytile[ch * 68 + tt], ytile[ch * 68 + tt + 1]);
    }
}

// ---------------------------------------------------------------------------
// Transpose g (b,c,l) -> gT (b,l,c) bf16.
// ---------------------------------------------------------------------------
__global__ __launch_bounds__(256) void transpose_g_kernel(
    const unsigned short* __restrict__ g_bcl, unsigned short* __restrict__ gT)
{
    __shared__ unsigned int tileU[64 * 33];
    const int t = threadIdx.x, ty = t >> 5, tx = t & 31;
    const int l0 = blockIdx.x * 64, c0 = blockIdx.y * 64, b = blockIdx.z;
    #pragma unroll
    for (int r = 0; r < 8; ++r) {
        const int ci = r * 8 + ty;
        tileU[ci * 33 + tx] =
            *(const unsigned int*)&g_bcl[((size_t)b * H_CH + c0 + ci) * LSEQ + l0 + tx * 2];
    }
    __syncthreads();
    #pragma unroll
    for (int r = 0; r < 8; ++r) {
        const int li = r * 8 + ty;
        unsigned int ua = tileU[(2 * tx) * 33 + (li >> 1)];
        unsigned int ub = tileU[(2 * tx + 1) * 33 + (li >> 1)];
        unsigned int s0 = (li & 1) ? (ua >> 16) : (ua & 0xffffu);
        unsigned int s1 = (li & 1) ? (ub >> 16) : (ub & 0xffffu);
        *(unsigned int*)&gT[((size_t)b * LSEQ + l0 + li) * H_CH + c0 + 2 * tx] =
            s0 | (s1 << 16);
    }
}

// ---------------------------------------------------------------------------
// W (k=1024, o=512) fp32 -> Wt (o=512, k=1024) bf16.
// ---------------------------------------------------------------------------
__global__ __launch_bounds__(256) void transpose_w_kernel(
    const float* __restrict__ W, unsigned short* __restrict__ Wt)
{
    __shared__ float tileF[64 * 65];
    const int t = threadIdx.x;
    const int o0 = blockIdx.x * 64, k0 = blockIdx.y * 64;
    {
        const int ty = t >> 6, tx = t & 63;
        #pragma unroll
        for (int r = 0; r < 16; ++r) {
            const int ki = r * 4 + ty;
            tileF[ki * 65 + tx] = W[(size_t)(k0 + ki) * OUTF + o0 + tx];
        }
    }
    __syncthreads();
    {
        const int ty = t >> 5, tx = t & 31;
        #pragma unroll
        for (int r = 0; r < 8; ++r) {
            const int oi = r * 8 + ty;
            unsigned int u0 = f2bf(tileF[(2 * tx) * 65 + oi]);
            unsigned int u1 = f2bf(tileF[(2 * tx + 1) * 65 + oi]);
            *(unsigned int*)&Wt[(size_t)(o0 + oi) * H_CH + k0 + 2 * tx] = u0 | (u1 << 16);
        }
    }
}

// ---------------------------------------------------------------------------
// GEMM: out[b,o,l] = sum_k Wt[o,k]*gT[b,l,k] + b_out[o].  (verified R2)
// ---------------------------------------------------------------------------
__global__ __launch_bounds__(256) void gemm_kernel(
    const unsigned short* __restrict__ gT, const unsigned short* __restrict__ Wt,
    const float* __restrict__ b_out, float* __restrict__ out)
{
    __shared__ unsigned short As[64 * 40];
    __shared__ unsigned short Bs[128 * 40];
    const int t = threadIdx.x, lane = t & 63, w = t >> 6;
    const int lm = lane & 15, lq = lane >> 4;
    const int l0 = blockIdx.x * 128, o0 = blockIdx.y * 64, bb = blockIdx.z;
    const unsigned short* gB = gT + (size_t)bb * LSEQ * H_CH;

    floatx4 acc[4][2];
    #pragma unroll
    for (int i = 0; i < 4; ++i)
        #pragma unroll
        for (int jj = 0; jj < 2; ++jj) acc[i][jj] = (floatx4){0.f, 0.f, 0.f, 0.f};

    for (int kt = 0; kt < 32; ++kt) {
        const int k0 = kt * 32;
        __syncthreads();
        {
            const int row = t >> 2, q = t & 3;
            *(uint4*)&As[row * 40 + q * 8] =
                *(const uint4*)(Wt + (size_t)(o0 + row) * H_CH + k0 + q * 8);
        }
        #pragma unroll
        for (int half = 0; half < 2; ++half) {
            const int chunk = t + half * 256, row = chunk >> 2, q = chunk & 3;
            *(uint4*)&Bs[row * 40 + q * 8] =
                *(const uint4*)(gB + (size_t)(l0 + row) * H_CH + k0 + q * 8);
        }
        __syncthreads();

        bf16x8 af[4], bfr[2];
        #pragma unroll
        for (int sm = 0; sm < 4; ++sm)
            af[sm] = *(const bf16x8*)&As[(sm * 16 + lm) * 40 + lq * 8];
        #pragma unroll
        for (int sn = 0; sn < 2; ++sn)
            bfr[sn] = *(const bf16x8*)&Bs[(w * 32 + sn * 16 + lm) * 40 + lq * 8];
        #pragma unroll
        for (int sm = 0; sm < 4; ++sm)
            #pragma unroll
            for (int sn = 0; sn < 2; ++sn)
                acc[sm][sn] = __builtin_amdgcn_mfma_f32_16x16x32_bf16(
                    af[sm], bfr[sn], acc[sm][sn], 0, 0, 0);
    }
    #pragma unroll
    for (int sm = 0; sm < 4; ++sm)
        #pragma unroll
        for (int sn = 0; sn < 2; ++sn)
            #pragma unroll
            for (int r = 0; r < 4; ++r) {
                const int o = o0 + sm * 16 + lq * 4 + r;
                const int l = l0 + w * 32 + sn * 16 + lm;
                out[((size_t)bb * OUTF + o) * LSEQ + l] = acc[sm][sn][r] + b_out[o];
            }
}

// ---------------------------------------------------------------------------
extern "C" void kernel_launch(void* const* d_in, const int* in_sizes, int n_in,
                              void* d_out, int out_size, void* d_ws, size_t ws_size,
                              hipStream_t stream) {
    const float* x      = (const float*)d_in[0];
    const float* log_dt = (const float*)d_in[1];
    const float* A_re   = (const float*)d_in[2];
    const float* A_im   = (const float*)d_in[3];
    const float* C_re   = (const float*)d_in[4];
    const float* C_im   = (const float*)d_in[5];
    const float* Dp     = (const float*)d_in[6];
    const float* W_out  = (const float*)d_in[7];
    const float* b_out  = (const float*)d_in[8];
    float* out = (float*)d_out;

    // Workspace overlays (66 MiB peak):
    //  [0,16M)   v (bf16)        -> gT after intra_inter
    //  [16M,48M) S  (bf16)       -> Wt after intra_inter
    //  [48M,64M) g (bf16)
    //  [64M,66M) coef (fp32 x8 per (c,n))
    char* ws = (char*)d_ws;
    unsigned short* vb   = (unsigned short*)ws;
    unsigned short* S    = (unsigned short*)(ws + (size_t)16 * 1024 * 1024);
    unsigned short* g    = (unsigned short*)(ws + (size_t)48 * 1024 * 1024);
    float*          coef = (float*)(ws + (size_t)64 * 1024 * 1024);
    unsigned short* gT   = (unsigned short*)ws;
    unsigned short* Wt   = (unsigned short*)(ws + (size_t)16 * 1024 * 1024);

    prep_v_kernel<<<2048, 256, 0, stream>>>(x, vb);
    coef_kernel<<<256, 256, 0, stream>>>(log_dt, A_re, A_im, C_re, C_im, coef);
    chunk_delta_kernel<<<2048, 256, 0, stream>>>(vb, coef, S);
    scan_kernel<<<512, 256, 0, stream>>>(coef, S);
    intra_inter_kernel<<<2048, 256, 0, stream>>>(vb, coef, S, Dp, g);
    transpose_g_kernel<<<dim3(64, 16, 2), 256, 0, stream>>>(g, gT);
    transpose_w_kernel<<<dim3(8, 16), 256, 0, stream>>>(W_out, Wt);
    gemm_kernel<<<dim3(32, 8, 2), 256, 0, stream>>>(gT, Wt, b_out, out);
}

// Round 4
// 157.036 us; speedup vs baseline: 2.1244x; 1.1639x over previous
//
#include <hip/hip_runtime.h>
#include <cstdint>
#include <cstddef>

#define H_CH 1024
#define OUTF 512
#define LSEQ 4096

typedef __bf16 bf16x8 __attribute__((ext_vector_type(8)));
typedef float floatx4 __attribute__((ext_vector_type(4)));

__device__ __forceinline__ unsigned short f2bf(float f) {
    __bf16 b = (__bf16)f;
    return __builtin_bit_cast(unsigned short, b);
}
__device__ __forceinline__ unsigned int pack2(float a, float b) {
    return (unsigned int)f2bf(a) | ((unsigned int)f2bf(b) << 16);
}
__device__ __forceinline__ float bf2f(unsigned short u) {
    unsigned int x = ((unsigned int)u) << 16;
    return __builtin_bit_cast(float, x);
}
struct c32 { float x, y; };
__device__ __forceinline__ c32 cmul(c32 a, c32 b) {
    return { fmaf(a.x, b.x, -a.y * b.y), fmaf(a.x, b.y, a.y * b.x) };
}
__device__ __forceinline__ c32 cpow16(c32 a, int w) {   // a^(16*w), w in 0..3
    c32 p = {1.f, 0.f};
    if (w) {
        c32 a2 = cmul(a, a), a4 = cmul(a2, a2), a8 = cmul(a4, a4), a16 = cmul(a8, a8);
        p = a16;
        for (int k = 1; k < w; ++k) p = cmul(p, a16);
    }
    return p;
}

// ---------------------------------------------------------------------------
// coef: per (c,n) fp64-exact {lam, inv=lam^-1, lamQ=lam^64, 2*conj-folded Ct}.
// ---------------------------------------------------------------------------
__global__ __launch_bounds__(256) void coef_kernel(
    const float* __restrict__ log_dt, const float* __restrict__ A_re,
    const float* __restrict__ A_im, const float* __restrict__ C_re,
    const float* __restrict__ C_im, float* __restrict__ coef)
{
    const int i = blockIdx.x * 256 + threadIdx.x;   // c*64+n
    const int c = i >> 6;
    double are = A_re[i], aim = A_im[i], cre = C_re[i], cim = C_im[i];
    double dt  = exp((double)log_dt[c]);
    double dar = dt * are, dai = dt * aim;
    double er = exp(dar), cd = cos(dai), sd = sin(dai);
    double lre = er * cd, limm = er * sd;
    double ei = exp(-dar);
    double eQ = exp(64.0 * dar), cQ = cos(64.0 * dai), sQ = sin(64.0 * dai);
    double nre = lre - 1.0, nim = limm;
    double d2  = are * are + aim * aim;
    double qre = (nre * are + nim * aim) / d2;
    double qim = (nim * are - nre * aim) / d2;
    double ctre = cre * qre - cim * qim, ctim = cre * qim + cim * qre;
    float4 w0 = make_float4((float)lre, (float)limm, (float)(ei * cd), (float)(-ei * sd));
    float4 w1 = make_float4((float)(eQ * cQ), (float)(eQ * sQ),
                            (float)(2.0 * ctre), (float)(-2.0 * ctim));
    *(float4*)&coef[(size_t)i * 8]     = w0;
    *(float4*)&coef[(size_t)i * 8 + 4] = w1;
}

// ---------------------------------------------------------------------------
// s4_fused: per (b,c) block does EVERYTHING:
//   x -> Vs(bf16,posenc) ; Delta = F@V (MFMA) -> Ss ; segmented chunk scan
//   (in-block) -> Shat ; Y = tril(P@R)@V + E@Shat ; +D*v ; gelu -> g[b,c,l].
// ---------------------------------------------------------------------------
__global__ __launch_bounds__(256) void s4_fused_kernel(
    const float* __restrict__ x, const float* __restrict__ coef,
    const float* __restrict__ Dp, unsigned short* __restrict__ g)
{
    __shared__ __align__(16) unsigned short Vs[64 * 72];      // [chunk][t]
    __shared__ __align__(16) unsigned short FP[128 * 72];     // Fs; later Ps[65*136]
    __shared__ __align__(16) unsigned short Ss[64 * 136];     // [chunk][comp] Delta->Shat
    __shared__ __align__(16) unsigned char  RY[64 * 136 * 2]; // Rs bf16 / ytile f32[64*68]
    __shared__ __align__(16) unsigned short Ts[64 * 72];
    __shared__ float2 Es[4][64];                              // per-wave scan end-states
    __shared__ float  pe16[16];
    unsigned short* Fs = FP;
    unsigned short* Ps = FP;                                  // stride 136, 65 rows
    unsigned short* Rs = (unsigned short*)RY;
    float* ytile = (float*)RY;

    const int wid = blockIdx.x;                 // b*1024 + c
    const int c = wid & (H_CH - 1);
    const int t = threadIdx.x, lane = t & 63, w = t >> 6, n = lane;
    const int lm = lane & 15, lq = lane >> 4;

    // --- posenc table (16 distinct values per channel) ---
    const int axis = (c >= 684) ? 2 : ((c >= 342) ? 1 : 0);
    const int j = c - 342 * axis;
    const int is_cos = j & 1;
    if (t < 16) {
        const float freq = (float)exp(-log(10000.0) * (double)(2 * (j >> 1)) / 342.0);
        float a = (float)t * freq;
        pe16[t] = is_cos ? cosf(a) : sinf(a);
    }

    const float* cf = coef + ((size_t)c * 64 + n) * 8;
    c32 lam = {cf[0], cf[1]}, inv = {cf[2], cf[3]}, lamQ = {cf[4], cf[5]};
    const float c2r = cf[6], c2mi = cf[7];
    const float Dc = Dp[c];
    __syncthreads();

    // --- stage V = bf16(x + posenc) ---
    const float* xp = x + (size_t)wid * LSEQ;
    #pragma unroll
    for (int r = 0; r < 2; ++r) {
        const int i = r * 256 + t, l0 = i * 8;
        float4 f0 = *(const float4*)(xp + l0);
        float4 f1 = *(const float4*)(xp + l0 + 4);
        float e[8] = {f0.x, f0.y, f0.z, f0.w, f1.x, f1.y, f1.z, f1.w};
        unsigned int o[4];
        #pragma unroll
        for (int k = 0; k < 4; ++k) {
            const int la = l0 + 2 * k, lb = la + 1;
            const int pa = axis == 0 ? (la >> 8) : axis == 1 ? ((la >> 4) & 15) : (la & 15);
            const int pb = axis == 0 ? (lb >> 8) : axis == 1 ? ((lb >> 4) & 15) : (lb & 15);
            o[k] = pack2(e[2 * k] + pe16[pa], e[2 * k + 1] + pe16[pb]);
        }
        *(uint4*)&Vs[(i >> 3) * 72 + (i & 7) * 8] = make_uint4(o[0], o[1], o[2], o[3]);
    }
    // --- F rows 2n,2n+1 : (Re,Im) lam^(63-u), u in [16w,16w+16) ---
    {
        c32 l2 = cmul(lam, lam), l4 = cmul(l2, l2), l8 = cmul(l4, l4);
        c32 l16 = cmul(l8, l8), l32 = cmul(l16, l16);
        c32 z = cmul(cmul(cmul(cmul(cmul(l32, l16), l8), l4), l2), lam); // lam^63
        z = cmul(z, cpow16(inv, w));
        #pragma unroll
        for (int s = 0; s < 16; ++s) {
            const int u = 16 * w + s;
            Fs[(2 * n) * 72 + u]     = f2bf(z.x);
            Fs[(2 * n + 1) * 72 + u] = f2bf(z.y);
            z = cmul(z, inv);
        }
    }
    __syncthreads();

    // --- Delta = F(128x64) @ V(64chunks x 64) ---
    {
        floatx4 acc[2][4];
        #pragma unroll
        for (int a = 0; a < 2; ++a)
            #pragma unroll
            for (int b = 0; b < 4; ++b) acc[a][b] = (floatx4){0.f, 0.f, 0.f, 0.f};
        #pragma unroll
        for (int kt = 0; kt < 2; ++kt) {
            bf16x8 a0 = *(const bf16x8*)&Fs[(32 * w + lm) * 72 + kt * 32 + lq * 8];
            bf16x8 a1 = *(const bf16x8*)&Fs[(32 * w + 16 + lm) * 72 + kt * 32 + lq * 8];
            #pragma unroll
            for (int nt = 0; nt < 4; ++nt) {
                bf16x8 b = *(const bf16x8*)&Vs[(nt * 16 + lm) * 72 + kt * 32 + lq * 8];
                acc[0][nt] = __builtin_amdgcn_mfma_f32_16x16x32_bf16(a0, b, acc[0][nt], 0, 0, 0);
                acc[1][nt] = __builtin_amdgcn_mfma_f32_16x16x32_bf16(a1, b, acc[1][nt], 0, 0, 0);
            }
        }
        __syncthreads();   // Fs reads done before Ps overlay; Ss not yet read
        #pragma unroll
        for (int sm = 0; sm < 2; ++sm)
            #pragma unroll
            for (int nt = 0; nt < 4; ++nt) {
                const int row = 32 * w + sm * 16 + lq * 4, col = nt * 16 + lm;
                *(uint2*)&Ss[col * 136 + row] =
                    make_uint2(pack2(acc[sm][nt][0], acc[sm][nt][1]),
                               pack2(acc[sm][nt][2], acc[sm][nt][3]));
            }
    }
    __syncthreads();

    // --- phase 3: build P,R ; scan pass A (local, zero-init) ---
    {   // P rows tt: (Re,-Im) of 2*Ct*lam^tt ; wave w covers [16w,16w+16) (+65th on w=3)
        c32 z = cmul((c32){c2r, -c2mi}, cpow16(lam, w));
        const int steps = (w == 3) ? 17 : 16;
        for (int s = 0; s < steps; ++s) {
            const int tt = 16 * w + s;
            *(unsigned int*)&Ps[tt * 136 + 2 * n] = pack2(z.x, -z.y);
            z = cmul(z, lam);
        }
    }
    {   // R rows u: (Re,Im) lam^-u
        c32 z = cpow16(inv, w);
        #pragma unroll
        for (int s = 0; s < 16; ++s) {
            const int u = 16 * w + s;
            *(unsigned int*)&Rs[u * 136 + 2 * n] = pack2(z.x, z.y);
            z = cmul(z, inv);
        }
    }
    {   // pass A: local scan of segment w
        float sr = 0.f, si = 0.f;
        #pragma unroll
        for (int jc = 0; jc < 16; ++jc) {
            unsigned int d = *(unsigned int*)&Ss[(16 * w + jc) * 136 + 2 * n];
            float dr = bf2f((unsigned short)(d & 0xffff));
            float di = bf2f((unsigned short)(d >> 16));
            float nr = fmaf(lamQ.x, sr, fmaf(-lamQ.y, si, dr));
            float ni = fmaf(lamQ.x, si, fmaf(lamQ.y, sr, di));
            sr = nr; si = ni;
        }
        Es[w][n] = make_float2(sr, si);
    }
    __syncthreads();

    // --- phase 4: cross-wave carry, pass B writes Shat into Ss ---
    {
        c32 Q2 = cmul(lamQ, lamQ), Q4 = cmul(Q2, Q2), Q8 = cmul(Q4, Q4);
        c32 Q16 = cmul(Q8, Q8);                       // lam^1024
        float cr = 0.f, ci = 0.f;
        for (int w2 = 0; w2 < w; ++w2) {
            float2 e = Es[w2][n];
            float nr = fmaf(Q16.x, cr, fmaf(-Q16.y, ci, e.x));
            float ni = fmaf(Q16.x, ci, fmaf(Q16.y, cr, e.y));
            cr = nr; ci = ni;
        }
        float sr = cr, si = ci;
        #pragma unroll
        for (int jc = 0; jc < 16; ++jc) {
            unsigned int* p = (unsigned int*)&Ss[(16 * w + jc) * 136 + 2 * n];
            unsigned int d = *p;
            *p = pack2(sr, si);
            float dr = bf2f((unsigned short)(d & 0xffff));
            float di = bf2f((unsigned short)(d >> 16));
            float nr = fmaf(lamQ.x, sr, fmaf(-lamQ.y, si, dr));
            float ni = fmaf(lamQ.x, si, fmaf(lamQ.y, sr, di));
            sr = nr; si = ni;
        }
    }
    __syncthreads();

    // --- GEMM1: T = tril(P@R), M=N=64, K=128 ---
    {
        floatx4 a1[4];
        #pragma unroll
        for (int nt = 0; nt < 4; ++nt) a1[nt] = (floatx4){0.f, 0.f, 0.f, 0.f};
        #pragma unroll
        for (int kt = 0; kt < 4; ++kt) {
            bf16x8 a = *(const bf16x8*)&Ps[(16 * w + lm) * 136 + kt * 32 + lq * 8];
            #pragma unroll
            for (int nt = 0; nt < 4; ++nt) {
                bf16x8 b = *(const bf16x8*)&Rs[(nt * 16 + lm) * 136 + kt * 32 + lq * 8];
                a1[nt] = __builtin_amdgcn_mfma_f32_16x16x32_bf16(a, b, a1[nt], 0, 0, 0);
            }
        }
        #pragma unroll
        for (int nt = 0; nt < 4; ++nt)
            #pragma unroll
            for (int r = 0; r < 4; ++r) {
                const int row = 16 * w + lq * 4 + r, col = nt * 16 + lm;
                Ts[row * 72 + col] = f2bf(row >= col ? a1[nt][r] : 0.f);
            }
    }
    __syncthreads();

    // --- GEMM2: Y = T@V + E@Shat ; epilogue -> ytile (overlays Rs) ---
    {
        floatx4 a2[4];
        #pragma unroll
        for (int nt = 0; nt < 4; ++nt) a2[nt] = (floatx4){0.f, 0.f, 0.f, 0.f};
        #pragma unroll
        for (int kt = 0; kt < 2; ++kt) {
            bf16x8 a = *(const bf16x8*)&Ts[(16 * w + lm) * 72 + kt * 32 + lq * 8];
            #pragma unroll
            for (int nt = 0; nt < 4; ++nt) {
                bf16x8 b = *(const bf16x8*)&Vs[(nt * 16 + lm) * 72 + kt * 32 + lq * 8];
                a2[nt] = __builtin_amdgcn_mfma_f32_16x16x32_bf16(a, b, a2[nt], 0, 0, 0);
            }
        }
        #pragma unroll
        for (int kt = 0; kt < 4; ++kt) {
            bf16x8 a = *(const bf16x8*)&Ps[(16 * w + lm + 1) * 136 + kt * 32 + lq * 8];
            #pragma unroll
            for (int nt = 0; nt < 4; ++nt) {
                bf16x8 b = *(const bf16x8*)&Ss[(nt * 16 + lm) * 136 + kt * 32 + lq * 8];
                a2[nt] = __builtin_amdgcn_mfma_f32_16x16x32_bf16(a, b, a2[nt], 0, 0, 0);
            }
        }
        #pragma unroll
        for (int nt = 0; nt < 4; ++nt)
            #pragma unroll
            for (int r = 0; r < 4; ++r) {
                const int tt = 16 * w + lq * 4 + r, chunk = nt * 16 + lm;
                const float vv = bf2f(Vs[chunk * 72 + tt]);
                const float y = fmaf(Dc, vv, a2[nt][r]);
                const float u = y + 0.044715f * y * y * y;
                const float gg = 0.5f * y * (1.f + tanhf(0.7978845608028654f * u));
                ytile[chunk * 68 + tt] = gg;
            }
    }
    __syncthreads();
    unsigned int* gp = (unsigned int*)(g + (size_t)wid * LSEQ);
    #pragma unroll
    for (int q = 0; q < 8; ++q) {
        const int idx = q * 256 + t, l = idx * 2;
        const int ch = l >> 6, tt = l & 63;
        gp[idx] = pack2(ytile[ch * 68 + tt], ytile[ch * 68 + tt + 1]);
    }
}

// ---------------------------------------------------------------------------
// Transpose g (b,c,l) -> gT (b,l,c) bf16.
// ---------------------------------------------------------------------------
__global__ __launch_bounds__(256) void transpose_g_kernel(
    const unsigned short* __restrict__ g_bcl, unsigned short* __restrict__ gT)
{
    __shared__ unsigned int tileU[64 * 33];
    const int t = threadIdx.x, ty = t >> 5, tx = t & 31;
    const int l0 = blockIdx.x * 64, c0 = blockIdx.y * 64, b = blockIdx.z;
    #pragma unroll
    for (int r = 0; r < 8; ++r) {
        const int ci = r * 8 + ty;
        tileU[ci * 33 + tx] =
            *(const unsigned int*)&g_bcl[((size_t)b * H_CH + c0 + ci) * LSEQ + l0 + tx * 2];
    }
    __syncthreads();
    #pragma unroll
    for (int r = 0; r < 8; ++r) {
        const int li = r * 8 + ty;
        unsigned int ua = tileU[(2 * tx) * 33 + (li >> 1)];
        unsigned int ub = tileU[(2 * tx + 1) * 33 + (li >> 1)];
        unsigned int s0 = (li & 1) ? (ua >> 16) : (ua & 0xffffu);
        unsigned int s1 = (li & 1) ? (ub >> 16) : (ub & 0xffffu);
        *(unsigned int*)&gT[((size_t)b * LSEQ + l0 + li) * H_CH + c0 + 2 * tx] =
            s0 | (s1 << 16);
    }
}

// ---------------------------------------------------------------------------
// W (k=1024, o=512) fp32 -> Wt (o=512, k=1024) bf16.
// ---------------------------------------------------------------------------
__global__ __launch_bounds__(256) void transpose_w_kernel(
    const float* __restrict__ W, unsigned short* __restrict__ Wt)
{
    __shared__ float tileF[64 * 65];
    const int t = threadIdx.x;
    const int o0 = blockIdx.x * 64, k0 = blockIdx.y * 64;
    {
        const int ty = t >> 6, tx = t & 63;
        #pragma unroll
        for (int r = 0; r < 16; ++r) {
            const int ki = r * 4 + ty;
            tileF[ki * 65 + tx] = W[(size_t)(k0 + ki) * OUTF + o0 + tx];
        }
    }
    __syncthreads();
    {
        const int ty = t >> 5, tx = t & 31;
        #pragma unroll
        for (int r = 0; r < 8; ++r) {
            const int oi = r * 8 + ty;
            unsigned int u0 = f2bf(tileF[(2 * tx) * 65 + oi]);
            unsigned int u1 = f2bf(tileF[(2 * tx + 1) * 65 + oi]);
            *(unsigned int*)&Wt[(size_t)(o0 + oi) * H_CH + k0 + 2 * tx] = u0 | (u1 << 16);
        }
    }
}

// ---------------------------------------------------------------------------
// GEMM: out[b,o,l] = sum_k Wt[o,k]*gT[b,l,k] + b_out[o].  (verified R2/R3)
// ---------------------------------------------------------------------------
__global__ __launch_bounds__(256) void gemm_kernel(
    const unsigned short* __restrict__ gT, const unsigned short* __restrict__ Wt,
    const float* __restrict__ b_out, float* __restrict__ out)
{
    __shared__ unsigned short As[64 * 40];
    __shared__ unsigned short Bs[128 * 40];
    const int t = threadIdx.x, lane = t & 63, w = t >> 6;
    const int lm = lane & 15, lq = lane >> 4;
    const int l0 = blockIdx.x * 128, o0 = blockIdx.y * 64, bb = blockIdx.z;
    const unsigned short* gB = gT + (size_t)bb * LSEQ * H_CH;

    floatx4 acc[4][2];
    #pragma unroll
    for (int i = 0; i < 4; ++i)
        #pragma unroll
        for (int jj = 0; jj < 2; ++jj) acc[i][jj] = (floatx4){0.f, 0.f, 0.f, 0.f};

    for (int kt = 0; kt < 32; ++kt) {
        const int k0 = kt * 32;
        __syncthreads();
        {
            const int row = t >> 2, q = t & 3;
            *(uint4*)&As[row * 40 + q * 8] =
                *(const uint4*)(Wt + (size_t)(o0 + row) * H_CH + k0 + q * 8);
        }
        #pragma unroll
        for (int half = 0; half < 2; ++half) {
            const int chunk = t + half * 256, row = chunk >> 2, q = chunk & 3;
            *(uint4*)&Bs[row * 40 + q * 8] =
                *(const uint4*)(gB + (size_t)(l0 + row) * H_CH + k0 + q * 8);
        }
        __syncthreads();

        bf16x8 af[4], bfr[2];
        #pragma unroll
        for (int sm = 0; sm < 4; ++sm)
            af[sm] = *(const bf16x8*)&As[(sm * 16 + lm) * 40 + lq * 8];
        #pragma unroll
        for (int sn = 0; sn < 2; ++sn)
            bfr[sn] = *(const bf16x8*)&Bs[(w * 32 + sn * 16 + lm) * 40 + lq * 8];
        #pragma unroll
        for (int sm = 0; sm < 4; ++sm)
            #pragma unroll
            for (int sn = 0; sn < 2; ++sn)
                acc[sm][sn] = __builtin_amdgcn_mfma_f32_16x16x32_bf16(
                    af[sm], bfr[sn], acc[sm][sn], 0, 0, 0);
    }
    #pragma unroll
    for (int sm = 0; sm < 4; ++sm)
        #pragma unroll
        for (int sn = 0; sn < 2; ++sn)
            #pragma unroll
            for (int r = 0; r < 4; ++r) {
                const int o = o0 + sm * 16 + lq * 4 + r;
                const int l = l0 + w * 32 + sn * 16 + lm;
                out[((size_t)bb * OUTF + o) * LSEQ + l] = acc[sm][sn][r] + b_out[o];
            }
}

// ---------------------------------------------------------------------------
extern "C" void kernel_launch(void* const* d_in, const int* in_sizes, int n_in,
                              void* d_out, int out_size, void* d_ws, size_t ws_size,
                              hipStream_t stream) {
    const float* x      = (const float*)d_in[0];
    const float* log_dt = (const float*)d_in[1];
    const float* A_re   = (const float*)d_in[2];
    const float* A_im   = (const float*)d_in[3];
    const float* C_re   = (const float*)d_in[4];
    const float* C_im   = (const float*)d_in[5];
    const float* Dp     = (const float*)d_in[6];
    const float* W_out  = (const float*)d_in[7];
    const float* b_out  = (const float*)d_in[8];
    float* out = (float*)d_out;

    // Workspace: g [0,16M), gT [16M,32M), Wt [32M,33M), coef [33M,35M)
    char* ws = (char*)d_ws;
    unsigned short* g    = (unsigned short*)ws;
    unsigned short* gT   = (unsigned short*)(ws + (size_t)16 * 1024 * 1024);
    unsigned short* Wt   = (unsigned short*)(ws + (size_t)32 * 1024 * 1024);
    float*          coef = (float*)(ws + (size_t)33 * 1024 * 1024);

    coef_kernel<<<256, 256, 0, stream>>>(log_dt, A_re, A_im, C_re, C_im, coef);
    s4_fused_kernel<<<2048, 256, 0, stream>>>(x, coef, Dp, g);
    transpose_g_kernel<<<dim3(64, 16, 2), 256, 0, stream>>>(g, gT);
    transpose_w_kernel<<<dim3(8, 16), 256, 0, stream>>>(W_out, Wt);
    gemm_kernel<<<dim3(32, 8, 2), 256, 0, stream>>>(gT, Wt, b_out, out);
}

// Round 5
// 147.668 us; speedup vs baseline: 2.2592x; 1.0634x over previous
//
#include <hip/hip_runtime.h>
#include <cstdint>
#include <cstddef>

#define H_CH 1024
#define OUTF 512
#define LSEQ 4096

typedef __bf16 bf16x8 __attribute__((ext_vector_type(8)));
typedef float floatx4 __attribute__((ext_vector_type(4)));

__device__ __forceinline__ unsigned short f2bf(float f) {
    __bf16 b = (__bf16)f;
    return __builtin_bit_cast(unsigned short, b);
}
__device__ __forceinline__ unsigned int pack2(float a, float b) {
    return (unsigned int)f2bf(a) | ((unsigned int)f2bf(b) << 16);
}
__device__ __forceinline__ float bf2f(unsigned short u) {
    unsigned int x = ((unsigned int)u) << 16;
    return __builtin_bit_cast(float, x);
}
struct c32 { float x, y; };
__device__ __forceinline__ c32 cmul(c32 a, c32 b) {
    return { fmaf(a.x, b.x, -a.y * b.y), fmaf(a.x, b.y, a.y * b.x) };
}
__device__ __forceinline__ c32 cpow16(c32 a, int w) {   // a^(16*w), w in 0..3
    c32 p = {1.f, 0.f};
    if (w) {
        c32 a2 = cmul(a, a), a4 = cmul(a2, a2), a8 = cmul(a4, a4), a16 = cmul(a8, a8);
        p = a16;
        for (int k = 1; k < w; ++k) p = cmul(p, a16);
    }
    return p;
}
// gelu(y) = y * sigmoid(1.59576912*(y + 0.044715 y^3))  (== tanh-GELU exactly)
__device__ __forceinline__ float gelu_fast(float y) {
    float u = y + 0.044715f * y * y * y;
    float e = __expf(-1.5957691216057308f * u);
    return y * __builtin_amdgcn_rcpf(1.f + e);
}

// ---------------------------------------------------------------------------
// coef: per (c,n) fp64-exact {lam, inv=lam^-1, lamQ=lam^64, 2*conj-folded Ct}.
// ---------------------------------------------------------------------------
__global__ __launch_bounds__(256) void coef_kernel(
    const float* __restrict__ log_dt, const float* __restrict__ A_re,
    const float* __restrict__ A_im, const float* __restrict__ C_re,
    const float* __restrict__ C_im, float* __restrict__ coef)
{
    const int i = blockIdx.x * 256 + threadIdx.x;   // c*64+n
    const int c = i >> 6;
    double are = A_re[i], aim = A_im[i], cre = C_re[i], cim = C_im[i];
    double dt  = exp((double)log_dt[c]);
    double dar = dt * are, dai = dt * aim;
    double er = exp(dar), cd = cos(dai), sd = sin(dai);
    double lre = er * cd, limm = er * sd;
    double ei = exp(-dar);
    double eQ = exp(64.0 * dar), cQ = cos(64.0 * dai), sQ = sin(64.0 * dai);
    double nre = lre - 1.0, nim = limm;
    double d2  = are * are + aim * aim;
    double qre = (nre * are + nim * aim) / d2;
    double qim = (nim * are - nre * aim) / d2;
    double ctre = cre * qre - cim * qim, ctim = cre * qim + cim * qre;
    float4 w0 = make_float4((float)lre, (float)limm, (float)(ei * cd), (float)(-ei * sd));
    float4 w1 = make_float4((float)(eQ * cQ), (float)(eQ * sQ),
                            (float)(2.0 * ctre), (float)(-2.0 * ctim));
    *(float4*)&coef[(size_t)i * 8]     = w0;
    *(float4*)&coef[(size_t)i * 8 + 4] = w1;
}

// ---------------------------------------------------------------------------
// s4_fused: one block per channel c, loops over both batches.
// Tables P,R and T=tril(P@R) are built ONCE per channel; per batch:
// V stage, F gen, Delta=F@V (MFMA), segmented scan, Y=T@V+E@Shat, gelu, store.
// ---------------------------------------------------------------------------
__global__ __launch_bounds__(256) void s4_fused_kernel(
    const float* __restrict__ x, const float* __restrict__ coef,
    const float* __restrict__ Dp, unsigned short* __restrict__ g)
{
    __shared__ __align__(16) unsigned short Vs[64 * 72];      // [chunk][t]
    __shared__ __align__(16) unsigned short Ps[65 * 136];     // P rows (bf16 pairs)
    __shared__ __align__(16) unsigned char  RY[128 * 72 * 2]; // F / R / ybuf overlay
    __shared__ __align__(16) unsigned short Ss[64 * 136];     // Delta -> Shat
    __shared__ __align__(16) unsigned short Ts[64 * 72];      // T = tril(P@R) bf16
    __shared__ float2 Es[4][64];
    __shared__ float  pe16[16];
    unsigned short* Fs   = (unsigned short*)RY;               // 128*72
    unsigned short* Rs   = (unsigned short*)RY;               // 64*136
    unsigned int*   ybuf = (unsigned int*)RY;                 // 64*34 u32

    const int c = blockIdx.x;                                 // 0..1023
    const int t = threadIdx.x, lane = t & 63, w = t >> 6, n = lane;
    const int lm = lane & 15, lq = lane >> 4;

    const int axis = (c >= 684) ? 2 : ((c >= 342) ? 1 : 0);
    const int j = c - 342 * axis;
    const int is_cos = j & 1;
    if (t < 16) {
        const float freq = (float)exp(-log(10000.0) * (double)(2 * (j >> 1)) / 342.0);
        float a = (float)t * freq;
        pe16[t] = is_cos ? cosf(a) : sinf(a);
    }
    const float* cf = coef + ((size_t)c * 64 + n) * 8;
    c32 lam = {cf[0], cf[1]}, inv = {cf[2], cf[3]}, lamQ = {cf[4], cf[5]};
    const float c2r = cf[6], c2mi = cf[7];
    const float Dc = Dp[c];
    __syncthreads();                                          // pe16 visible

    // --- per-batch: stage V, gen F, Delta, segmented scan -> Shat in Ss ---
    auto deltascan = [&](int bb) {
        const float* xp = x + ((size_t)bb * H_CH + c) * (size_t)LSEQ;
        #pragma unroll
        for (int r = 0; r < 2; ++r) {
            const int i = r * 256 + t, l0 = i * 8;
            float4 f0 = *(const float4*)(xp + l0);
            float4 f1 = *(const float4*)(xp + l0 + 4);
            float e[8] = {f0.x, f0.y, f0.z, f0.w, f1.x, f1.y, f1.z, f1.w};
            unsigned int o[4];
            #pragma unroll
            for (int k = 0; k < 4; ++k) {
                const int la = l0 + 2 * k, lb = la + 1;
                const int pa = axis == 0 ? (la >> 8) : axis == 1 ? ((la >> 4) & 15) : (la & 15);
                const int pb = axis == 0 ? (lb >> 8) : axis == 1 ? ((lb >> 4) & 15) : (lb & 15);
                o[k] = pack2(e[2 * k] + pe16[pa], e[2 * k + 1] + pe16[pb]);
            }
            *(uint4*)&Vs[(i >> 3) * 72 + (i & 7) * 8] = make_uint4(o[0], o[1], o[2], o[3]);
        }
        {   // F rows 2n,2n+1: (Re,Im) lam^(63-u), u in [16w,16w+16)
            c32 l2 = cmul(lam, lam), l4 = cmul(l2, l2), l8 = cmul(l4, l4);
            c32 l16 = cmul(l8, l8), l32 = cmul(l16, l16);
            c32 z = cmul(cmul(cmul(cmul(cmul(l32, l16), l8), l4), l2), lam); // lam^63
            z = cmul(z, cpow16(inv, w));
            #pragma unroll
            for (int s = 0; s < 16; ++s) {
                const int u = 16 * w + s;
                Fs[(2 * n) * 72 + u]     = f2bf(z.x);
                Fs[(2 * n + 1) * 72 + u] = f2bf(z.y);
                z = cmul(z, inv);
            }
        }
        __syncthreads();
        {   // Delta = F(128x64) @ V(64x64) -> scatter into Ss [chunk][comp]
            floatx4 acc[2][4];
            #pragma unroll
            for (int a = 0; a < 2; ++a)
                #pragma unroll
                for (int b = 0; b < 4; ++b) acc[a][b] = (floatx4){0.f, 0.f, 0.f, 0.f};
            #pragma unroll
            for (int kt = 0; kt < 2; ++kt) {
                bf16x8 a0 = *(const bf16x8*)&Fs[(32 * w + lm) * 72 + kt * 32 + lq * 8];
                bf16x8 a1 = *(const bf16x8*)&Fs[(32 * w + 16 + lm) * 72 + kt * 32 + lq * 8];
                #pragma unroll
                for (int nt = 0; nt < 4; ++nt) {
                    bf16x8 b = *(const bf16x8*)&Vs[(nt * 16 + lm) * 72 + kt * 32 + lq * 8];
                    acc[0][nt] = __builtin_amdgcn_mfma_f32_16x16x32_bf16(a0, b, acc[0][nt], 0, 0, 0);
                    acc[1][nt] = __builtin_amdgcn_mfma_f32_16x16x32_bf16(a1, b, acc[1][nt], 0, 0, 0);
                }
            }
            #pragma unroll
            for (int sm = 0; sm < 2; ++sm)
                #pragma unroll
                for (int nt = 0; nt < 4; ++nt) {
                    const int row = 32 * w + sm * 16 + lq * 4, col = nt * 16 + lm;
                    *(uint2*)&Ss[col * 136 + row] =
                        make_uint2(pack2(acc[sm][nt][0], acc[sm][nt][1]),
                                   pack2(acc[sm][nt][2], acc[sm][nt][3]));
                }
        }
        __syncthreads();
        {   // scan A: local (zero-init) scan of 16-chunk segment
            float sr = 0.f, si = 0.f;
            #pragma unroll
            for (int jc = 0; jc < 16; ++jc) {
                unsigned int d = *(unsigned int*)&Ss[(16 * w + jc) * 136 + 2 * n];
                float dr = bf2f((unsigned short)(d & 0xffff));
                float di = bf2f((unsigned short)(d >> 16));
                float nr = fmaf(lamQ.x, sr, fmaf(-lamQ.y, si, dr));
                float ni = fmaf(lamQ.x, si, fmaf(lamQ.y, sr, di));
                sr = nr; si = ni;
            }
            Es[w][n] = make_float2(sr, si);
        }
        __syncthreads();
        {   // carry + scan B -> exclusive Shat written back to Ss
            c32 Q2 = cmul(lamQ, lamQ), Q4 = cmul(Q2, Q2), Q8 = cmul(Q4, Q4);
            c32 Q16 = cmul(Q8, Q8);                       // lam^1024
            float cr = 0.f, ci = 0.f;
            for (int w2 = 0; w2 < w; ++w2) {
                float2 e = Es[w2][n];
                float nr = fmaf(Q16.x, cr, fmaf(-Q16.y, ci, e.x));
                float ni = fmaf(Q16.x, ci, fmaf(Q16.y, cr, e.y));
                cr = nr; ci = ni;
            }
            float sr = cr, si = ci;
            #pragma unroll
            for (int jc = 0; jc < 16; ++jc) {
                unsigned int* p = (unsigned int*)&Ss[(16 * w + jc) * 136 + 2 * n];
                unsigned int d = *p;
                *p = pack2(sr, si);
                float dr = bf2f((unsigned short)(d & 0xffff));
                float di = bf2f((unsigned short)(d >> 16));
                float nr = fmaf(lamQ.x, sr, fmaf(-lamQ.y, si, dr));
                float ni = fmaf(lamQ.x, si, fmaf(lamQ.y, sr, di));
                sr = nr; si = ni;
            }
        }
        __syncthreads();
    };

    // --- per-batch: Y = T@V + E@Shat ; gelu ; store g ---
    auto gemm2_epi = [&](int bb) {
        floatx4 a2[4];
        #pragma unroll
        for (int nt = 0; nt < 4; ++nt) a2[nt] = (floatx4){0.f, 0.f, 0.f, 0.f};
        #pragma unroll
        for (int kt = 0; kt < 2; ++kt) {
            bf16x8 a = *(const bf16x8*)&Ts[(16 * w + lm) * 72 + kt * 32 + lq * 8];
            #pragma unroll
            for (int nt = 0; nt < 4; ++nt) {
                bf16x8 b = *(const bf16x8*)&Vs[(nt * 16 + lm) * 72 + kt * 32 + lq * 8];
                a2[nt] = __builtin_amdgcn_mfma_f32_16x16x32_bf16(a, b, a2[nt], 0, 0, 0);
            }
        }
        #pragma unroll
        for (int kt = 0; kt < 4; ++kt) {
            bf16x8 a = *(const bf16x8*)&Ps[(16 * w + lm + 1) * 136 + kt * 32 + lq * 8];
            #pragma unroll
            for (int nt = 0; nt < 4; ++nt) {
                bf16x8 b = *(const bf16x8*)&Ss[(nt * 16 + lm) * 136 + kt * 32 + lq * 8];
                a2[nt] = __builtin_amdgcn_mfma_f32_16x16x32_bf16(a, b, a2[nt], 0, 0, 0);
            }
        }
        __syncthreads();   // RY readers (GEMM1 / Delta) done; safe to write ybuf
        #pragma unroll
        for (int nt = 0; nt < 4; ++nt) {
            const int chunk = nt * 16 + lm;
            float gg[4];
            #pragma unroll
            for (int r = 0; r < 4; ++r) {
                const int tt = 16 * w + lq * 4 + r;
                const float vv = bf2f(Vs[chunk * 72 + tt]);
                gg[r] = gelu_fast(fmaf(Dc, vv, a2[nt][r]));
            }
            const int p0 = 8 * w + 2 * lq;
            ybuf[chunk * 34 + p0]     = pack2(gg[0], gg[1]);
            ybuf[chunk * 34 + p0 + 1] = pack2(gg[2], gg[3]);
        }
        __syncthreads();
        unsigned int* gp = (unsigned int*)(g + ((size_t)bb * H_CH + c) * (size_t)LSEQ);
        #pragma unroll
        for (int q = 0; q < 8; ++q) {
            const int idx = q * 256 + t;
            gp[idx] = ybuf[(idx >> 5) * 34 + (idx & 31)];
        }
        __syncthreads();
    };

    // ---- pipeline ----
    deltascan(0);

    {   // P rows tt: (Re,-Im) of 2*Ct*lam^tt ; wave w covers [16w,16w+16) (+row 64 on w=3)
        c32 z = cmul((c32){c2r, -c2mi}, cpow16(lam, w));
        const int steps = (w == 3) ? 17 : 16;
        for (int s = 0; s < steps; ++s) {
            const int tt = 16 * w + s;
            *(unsigned int*)&Ps[tt * 136 + 2 * n] = pack2(z.x, -z.y);
            z = cmul(z, lam);
        }
    }
    {   // R rows u: (Re,Im) lam^-u  (overwrites F, which is dead post-Delta0)
        c32 z = cpow16(inv, w);
        #pragma unroll
        for (int s = 0; s < 16; ++s) {
            const int u = 16 * w + s;
            *(unsigned int*)&Rs[u * 136 + 2 * n] = pack2(z.x, z.y);
            z = cmul(z, inv);
        }
    }
    __syncthreads();
    {   // GEMM1: T = tril(P@R), M=N=64, K=128  (once per channel)
        floatx4 a1[4];
        #pragma unroll
        for (int nt = 0; nt < 4; ++nt) a1[nt] = (floatx4){0.f, 0.f, 0.f, 0.f};
        #pragma unroll
        for (int kt = 0; kt < 4; ++kt) {
            bf16x8 a = *(const bf16x8*)&Ps[(16 * w + lm) * 136 + kt * 32 + lq * 8];
            #pragma unroll
            for (int nt = 0; nt < 4; ++nt) {
                bf16x8 b = *(const bf16x8*)&Rs[(nt * 16 + lm) * 136 + kt * 32 + lq * 8];
                a1[nt] = __builtin_amdgcn_mfma_f32_16x16x32_bf16(a, b, a1[nt], 0, 0, 0);
            }
        }
        #pragma unroll
        for (int nt = 0; nt < 4; ++nt)
            #pragma unroll
            for (int r = 0; r < 4; ++r) {
                const int row = 16 * w + lq * 4 + r, col = nt * 16 + lm;
                Ts[row * 72 + col] = f2bf(row >= col ? a1[nt][r] : 0.f);
            }
    }
    __syncthreads();

    gemm2_epi(0);
    deltascan(1);
    gemm2_epi(1);
}

// ---------------------------------------------------------------------------
// Transpose g (b,c,l) -> gT (b,l,c) bf16.
// ---------------------------------------------------------------------------
__global__ __launch_bounds__(256) void transpose_g_kernel(
    const unsigned short* __restrict__ g_bcl, unsigned short* __restrict__ gT)
{
    __shared__ unsigned int tileU[64 * 33];
    const int t = threadIdx.x, ty = t >> 5, tx = t & 31;
    const int l0 = blockIdx.x * 64, c0 = blockIdx.y * 64, b = blockIdx.z;
    #pragma unroll
    for (int r = 0; r < 8; ++r) {
        const int ci = r * 8 + ty;
        tileU[ci * 33 + tx] =
            *(const unsigned int*)&g_bcl[((size_t)b * H_CH + c0 + ci) * LSEQ + l0 + tx * 2];
    }
    __syncthreads();
    #pragma unroll
    for (int r = 0; r < 8; ++r) {
        const int li = r * 8 + ty;
        unsigned int ua = tileU[(2 * tx) * 33 + (li >> 1)];
        unsigned int ub = tileU[(2 * tx + 1) * 33 + (li >> 1)];
        unsigned int s0 = (li & 1) ? (ua >> 16) : (ua & 0xffffu);
        unsigned int s1 = (li & 1) ? (ub >> 16) : (ub & 0xffffu);
        *(unsigned int*)&gT[((size_t)b * LSEQ + l0 + li) * H_CH + c0 + 2 * tx] =
            s0 | (s1 << 16);
    }
}

// ---------------------------------------------------------------------------
// W (k=1024, o=512) fp32 -> Wt (o=512, k=1024) bf16.
// ---------------------------------------------------------------------------
__global__ __launch_bounds__(256) void transpose_w_kernel(
    const float* __restrict__ W, unsigned short* __restrict__ Wt)
{
    __shared__ float tileF[64 * 65];
    const int t = threadIdx.x;
    const int o0 = blockIdx.x * 64, k0 = blockIdx.y * 64;
    {
        const int ty = t >> 6, tx = t & 63;
        #pragma unroll
        for (int r = 0; r < 16; ++r) {
            const int ki = r * 4 + ty;
            tileF[ki * 65 + tx] = W[(size_t)(k0 + ki) * OUTF + o0 + tx];
        }
    }
    __syncthreads();
    {
        const int ty = t >> 5, tx = t & 31;
        #pragma unroll
        for (int r = 0; r < 8; ++r) {
            const int oi = r * 8 + ty;
            unsigned int u0 = f2bf(tileF[(2 * tx) * 65 + oi]);
            unsigned int u1 = f2bf(tileF[(2 * tx + 1) * 65 + oi]);
            *(unsigned int*)&Wt[(size_t)(o0 + oi) * H_CH + k0 + 2 * tx] = u0 | (u1 << 16);
        }
    }
}

// ---------------------------------------------------------------------------
// GEMM: out[b,o,l] = sum_k Wt[o,k]*gT[b,l,k] + b_out[o].
// 128x128x32 tiles (R1-verified), 4 waves of 64x64.
// ---------------------------------------------------------------------------
__global__ __launch_bounds__(256) void gemm_kernel(
    const unsigned short* __restrict__ gT, const unsigned short* __restrict__ Wt,
    const float* __restrict__ b_out, float* __restrict__ out)
{
    __shared__ unsigned short As[128 * 40];
    __shared__ unsigned short Bs[128 * 40];
    const int t = threadIdx.x, lane = t & 63, wid = t >> 6;
    const int wo = wid & 1, wl = wid >> 1;
    const int lm = lane & 15, lq = lane >> 4;
    const int l0 = blockIdx.x * 128, o0 = blockIdx.y * 128, bb = blockIdx.z;
    const unsigned short* gB = gT + (size_t)bb * LSEQ * H_CH;

    floatx4 acc[4][4];
    #pragma unroll
    for (int i = 0; i < 4; ++i)
        #pragma unroll
        for (int jj = 0; jj < 4; ++jj) acc[i][jj] = (floatx4){0.f, 0.f, 0.f, 0.f};

    for (int kt = 0; kt < 32; ++kt) {
        const int k0 = kt * 32;
        __syncthreads();
        #pragma unroll
        for (int half = 0; half < 2; ++half) {
            const int chunk = t + half * 256;
            const int row = chunk >> 2, q = chunk & 3;
            *(uint4*)&As[row * 40 + q * 8] =
                *(const uint4*)(Wt + (size_t)(o0 + row) * H_CH + k0 + q * 8);
            *(uint4*)&Bs[row * 40 + q * 8] =
                *(const uint4*)(gB + (size_t)(l0 + row) * H_CH + k0 + q * 8);
        }
        __syncthreads();

        bf16x8 af[4], bfr[4];
        #pragma unroll
        for (int sm = 0; sm < 4; ++sm)
            af[sm] = *(const bf16x8*)&As[(wo * 64 + sm * 16 + lm) * 40 + lq * 8];
        #pragma unroll
        for (int sn = 0; sn < 4; ++sn)
            bfr[sn] = *(const bf16x8*)&Bs[(wl * 64 + sn * 16 + lm) * 40 + lq * 8];
        #pragma unroll
        for (int sm = 0; sm < 4; ++sm)
            #pragma unroll
            for (int sn = 0; sn < 4; ++sn)
                acc[sm][sn] = __builtin_amdgcn_mfma_f32_16x16x32_bf16(
                    af[sm], bfr[sn], acc[sm][sn], 0, 0, 0);
    }

    #pragma unroll
    for (int sm = 0; sm < 4; ++sm)
        #pragma unroll
        for (int sn = 0; sn < 4; ++sn)
            #pragma unroll
            for (int r = 0; r < 4; ++r) {
                const int o = o0 + wo * 64 + sm * 16 + lq * 4 + r;
                const int l = l0 + wl * 64 + sn * 16 + lm;
                out[((size_t)bb * OUTF + o) * LSEQ + l] = acc[sm][sn][r] + b_out[o];
            }
}

// ---------------------------------------------------------------------------
extern "C" void kernel_launch(void* const* d_in, const int* in_sizes, int n_in,
                              void* d_out, int out_size, void* d_ws, size_t ws_size,
                              hipStream_t stream) {
    const float* x      = (const float*)d_in[0];
    const float* log_dt = (const float*)d_in[1];
    const float* A_re   = (const float*)d_in[2];
    const float* A_im   = (const float*)d_in[3];
    const float* C_re   = (const float*)d_in[4];
    const float* C_im   = (const float*)d_in[5];
    const float* Dp     = (const float*)d_in[6];
    const float* W_out  = (const float*)d_in[7];
    const float* b_out  = (const float*)d_in[8];
    float* out = (float*)d_out;

    // Workspace: g [0,16M), gT [16M,32M), Wt [32M,33M), coef [33M,35M)
    char* ws = (char*)d_ws;
    unsigned short* g    = (unsigned short*)ws;
    unsigned short* gT   = (unsigned short*)(ws + (size_t)16 * 1024 * 1024);
    unsigned short* Wt   = (unsigned short*)(ws + (size_t)32 * 1024 * 1024);
    float*          coef = (float*)(ws + (size_t)33 * 1024 * 1024);

    coef_kernel<<<256, 256, 0, stream>>>(log_dt, A_re, A_im, C_re, C_im, coef);
    s4_fused_kernel<<<1024, 256, 0, stream>>>(x, coef, Dp, g);
    transpose_g_kernel<<<dim3(64, 16, 2), 256, 0, stream>>>(g, gT);
    transpose_w_kernel<<<dim3(8, 16), 256, 0, stream>>>(W_out, Wt);
    gemm_kernel<<<dim3(32, 4, 2), 256, 0, stream>>>(gT, Wt, b_out, out);
}

// Round 6
// 146.373 us; speedup vs baseline: 2.2791x; 1.0088x over previous
//
#include <hip/hip_runtime.h>
#include <cstdint>
#include <cstddef>

#define H_CH 1024
#define OUTF 512
#define LSEQ 4096

typedef __bf16 bf16x8 __attribute__((ext_vector_type(8)));
typedef float floatx4 __attribute__((ext_vector_type(4)));

__device__ __forceinline__ unsigned short f2bf(float f) {
    __bf16 b = (__bf16)f;
    return __builtin_bit_cast(unsigned short, b);
}
__device__ __forceinline__ unsigned int pack2(float a, float b) {
    return (unsigned int)f2bf(a) | ((unsigned int)f2bf(b) << 16);
}
__device__ __forceinline__ float bf2f(unsigned short u) {
    unsigned int x = ((unsigned int)u) << 16;
    return __builtin_bit_cast(float, x);
}
struct c32 { float x, y; };
__device__ __forceinline__ c32 cmul(c32 a, c32 b) {
    return { fmaf(a.x, b.x, -a.y * b.y), fmaf(a.x, b.y, a.y * b.x) };
}
__device__ __forceinline__ c32 cpow16(c32 a, int w) {   // a^(16*w), w in 0..3
    c32 p = {1.f, 0.f};
    if (w) {
        c32 a2 = cmul(a, a), a4 = cmul(a2, a2), a8 = cmul(a4, a4), a16 = cmul(a8, a8);
        p = a16;
        for (int k = 1; k < w; ++k) p = cmul(p, a16);
    }
    return p;
}
// gelu(y) = y * sigmoid(1.59576912*(y + 0.044715 y^3))  (== tanh-GELU exactly)
__device__ __forceinline__ float gelu_fast(float y) {
    float u = y + 0.044715f * y * y * y;
    float e = __expf(-1.5957691216057308f * u);
    return y * __builtin_amdgcn_rcpf(1.f + e);
}

// ---------------------------------------------------------------------------
// coef: per (c,n) fp64-exact {lam, inv=lam^-1, lamQ=lam^64, 2*conj-folded Ct}.
// ---------------------------------------------------------------------------
__global__ __launch_bounds__(256) void coef_kernel(
    const float* __restrict__ log_dt, const float* __restrict__ A_re,
    const float* __restrict__ A_im, const float* __restrict__ C_re,
    const float* __restrict__ C_im, float* __restrict__ coef)
{
    const int i = blockIdx.x * 256 + threadIdx.x;   // c*64+n
    const int c = i >> 6;
    double are = A_re[i], aim = A_im[i], cre = C_re[i], cim = C_im[i];
    double dt  = exp((double)log_dt[c]);
    double dar = dt * are, dai = dt * aim;
    double er = exp(dar), cd = cos(dai), sd = sin(dai);
    double lre = er * cd, limm = er * sd;
    double ei = exp(-dar);
    double eQ = exp(64.0 * dar), cQ = cos(64.0 * dai), sQ = sin(64.0 * dai);
    double nre = lre - 1.0, nim = limm;
    double d2  = are * are + aim * aim;
    double qre = (nre * are + nim * aim) / d2;
    double qim = (nim * are - nre * aim) / d2;
    double ctre = cre * qre - cim * qim, ctim = cre * qim + cim * qre;
    float4 w0 = make_float4((float)lre, (float)limm, (float)(ei * cd), (float)(-ei * sd));
    float4 w1 = make_float4((float)(eQ * cQ), (float)(eQ * sQ),
                            (float)(2.0 * ctre), (float)(-2.0 * ctim));
    *(float4*)&coef[(size_t)i * 8]     = w0;
    *(float4*)&coef[(size_t)i * 8 + 4] = w1;
}

// ---------------------------------------------------------------------------
// s4_fused: one block per channel c, loops over both batches.
// Output g' in l-tile-blocked layout: g'[b][l>>7][c][l&127] (bf16) so the
// GEMM's B-tiles are contiguous 8 KB blocks.
// ---------------------------------------------------------------------------
__global__ __launch_bounds__(256) void s4_fused_kernel(
    const float* __restrict__ x, const float* __restrict__ coef,
    const float* __restrict__ Dp, unsigned short* __restrict__ gprime)
{
    __shared__ __align__(16) unsigned short Vs[64 * 72];      // [chunk][t]
    __shared__ __align__(16) unsigned short Ps[65 * 136];     // P rows (bf16 pairs)
    __shared__ __align__(16) unsigned char  RY[128 * 72 * 2]; // F / R / ybuf overlay
    __shared__ __align__(16) unsigned short Ss[64 * 136];     // Delta -> Shat
    __shared__ __align__(16) unsigned short Ts[64 * 72];      // T = tril(P@R) bf16
    __shared__ float2 Es[4][64];
    __shared__ float  pe16[16];
    unsigned short* Fs   = (unsigned short*)RY;               // 128*72
    unsigned short* Rs   = (unsigned short*)RY;               // 64*136
    unsigned int*   ybuf = (unsigned int*)RY;                 // 64*34 u32

    const int c = blockIdx.x;                                 // 0..1023
    const int t = threadIdx.x, lane = t & 63, w = t >> 6, n = lane;
    const int lm = lane & 15, lq = lane >> 4;

    const int axis = (c >= 684) ? 2 : ((c >= 342) ? 1 : 0);
    const int j = c - 342 * axis;
    const int is_cos = j & 1;
    if (t < 16) {
        const float freq = (float)exp(-log(10000.0) * (double)(2 * (j >> 1)) / 342.0);
        float a = (float)t * freq;
        pe16[t] = is_cos ? cosf(a) : sinf(a);
    }
    const float* cf = coef + ((size_t)c * 64 + n) * 8;
    c32 lam = {cf[0], cf[1]}, inv = {cf[2], cf[3]}, lamQ = {cf[4], cf[5]};
    const float c2r = cf[6], c2mi = cf[7];
    const float Dc = Dp[c];
    __syncthreads();                                          // pe16 visible

    // --- per-batch: stage V, gen F, Delta, segmented scan -> Shat in Ss ---
    auto deltascan = [&](int bb) {
        const float* xp = x + ((size_t)bb * H_CH + c) * (size_t)LSEQ;
        #pragma unroll
        for (int r = 0; r < 2; ++r) {
            const int i = r * 256 + t, l0 = i * 8;
            float4 f0 = *(const float4*)(xp + l0);
            float4 f1 = *(const float4*)(xp + l0 + 4);
            float e[8] = {f0.x, f0.y, f0.z, f0.w, f1.x, f1.y, f1.z, f1.w};
            unsigned int o[4];
            #pragma unroll
            for (int k = 0; k < 4; ++k) {
                const int la = l0 + 2 * k, lb = la + 1;
                const int pa = axis == 0 ? (la >> 8) : axis == 1 ? ((la >> 4) & 15) : (la & 15);
                const int pb = axis == 0 ? (lb >> 8) : axis == 1 ? ((lb >> 4) & 15) : (lb & 15);
                o[k] = pack2(e[2 * k] + pe16[pa], e[2 * k + 1] + pe16[pb]);
            }
            *(uint4*)&Vs[(i >> 3) * 72 + (i & 7) * 8] = make_uint4(o[0], o[1], o[2], o[3]);
        }
        {   // F rows 2n,2n+1: (Re,Im) lam^(63-u), u in [16w,16w+16)
            c32 l2 = cmul(lam, lam), l4 = cmul(l2, l2), l8 = cmul(l4, l4);
            c32 l16 = cmul(l8, l8), l32 = cmul(l16, l16);
            c32 z = cmul(cmul(cmul(cmul(cmul(l32, l16), l8), l4), l2), lam); // lam^63
            z = cmul(z, cpow16(inv, w));
            #pragma unroll
            for (int s = 0; s < 16; ++s) {
                const int u = 16 * w + s;
                Fs[(2 * n) * 72 + u]     = f2bf(z.x);
                Fs[(2 * n + 1) * 72 + u] = f2bf(z.y);
                z = cmul(z, inv);
            }
        }
        __syncthreads();
        {   // Delta = F(128x64) @ V(64x64) -> scatter into Ss [chunk][comp]
            floatx4 acc[2][4];
            #pragma unroll
            for (int a = 0; a < 2; ++a)
                #pragma unroll
                for (int b = 0; b < 4; ++b) acc[a][b] = (floatx4){0.f, 0.f, 0.f, 0.f};
            #pragma unroll
            for (int kt = 0; kt < 2; ++kt) {
                bf16x8 a0 = *(const bf16x8*)&Fs[(32 * w + lm) * 72 + kt * 32 + lq * 8];
                bf16x8 a1 = *(const bf16x8*)&Fs[(32 * w + 16 + lm) * 72 + kt * 32 + lq * 8];
                #pragma unroll
                for (int nt = 0; nt < 4; ++nt) {
                    bf16x8 b = *(const bf16x8*)&Vs[(nt * 16 + lm) * 72 + kt * 32 + lq * 8];
                    acc[0][nt] = __builtin_amdgcn_mfma_f32_16x16x32_bf16(a0, b, acc[0][nt], 0, 0, 0);
                    acc[1][nt] = __builtin_amdgcn_mfma_f32_16x16x32_bf16(a1, b, acc[1][nt], 0, 0, 0);
                }
            }
            #pragma unroll
            for (int sm = 0; sm < 2; ++sm)
                #pragma unroll
                for (int nt = 0; nt < 4; ++nt) {
                    const int row = 32 * w + sm * 16 + lq * 4, col = nt * 16 + lm;
                    *(uint2*)&Ss[col * 136 + row] =
                        make_uint2(pack2(acc[sm][nt][0], acc[sm][nt][1]),
                                   pack2(acc[sm][nt][2], acc[sm][nt][3]));
                }
        }
        __syncthreads();
        {   // scan A: local (zero-init) scan of 16-chunk segment
            float sr = 0.f, si = 0.f;
            #pragma unroll
            for (int jc = 0; jc < 16; ++jc) {
                unsigned int d = *(unsigned int*)&Ss[(16 * w + jc) * 136 + 2 * n];
                float dr = bf2f((unsigned short)(d & 0xffff));
                float di = bf2f((unsigned short)(d >> 16));
                float nr = fmaf(lamQ.x, sr, fmaf(-lamQ.y, si, dr));
                float ni = fmaf(lamQ.x, si, fmaf(lamQ.y, sr, di));
                sr = nr; si = ni;
            }
            Es[w][n] = make_float2(sr, si);
        }
        __syncthreads();
        {   // carry + scan B -> exclusive Shat written back to Ss
            c32 Q2 = cmul(lamQ, lamQ), Q4 = cmul(Q2, Q2), Q8 = cmul(Q4, Q4);
            c32 Q16 = cmul(Q8, Q8);                       // lam^1024
            float cr = 0.f, ci = 0.f;
            for (int w2 = 0; w2 < w; ++w2) {
                float2 e = Es[w2][n];
                float nr = fmaf(Q16.x, cr, fmaf(-Q16.y, ci, e.x));
                float ni = fmaf(Q16.x, ci, fmaf(Q16.y, cr, e.y));
                cr = nr; ci = ni;
            }
            float sr = cr, si = ci;
            #pragma unroll
            for (int jc = 0; jc < 16; ++jc) {
                unsigned int* p = (unsigned int*)&Ss[(16 * w + jc) * 136 + 2 * n];
                unsigned int d = *p;
                *p = pack2(sr, si);
                float dr = bf2f((unsigned short)(d & 0xffff));
                float di = bf2f((unsigned short)(d >> 16));
                float nr = fmaf(lamQ.x, sr, fmaf(-lamQ.y, si, dr));
                float ni = fmaf(lamQ.x, si, fmaf(lamQ.y, sr, di));
                sr = nr; si = ni;
            }
        }
        __syncthreads();
    };

    // --- per-batch: Y = T@V + E@Shat ; gelu ; store g' (blocked layout) ---
    auto gemm2_epi = [&](int bb) {
        floatx4 a2[4];
        #pragma unroll
        for (int nt = 0; nt < 4; ++nt) a2[nt] = (floatx4){0.f, 0.f, 0.f, 0.f};
        #pragma unroll
        for (int kt = 0; kt < 2; ++kt) {
            bf16x8 a = *(const bf16x8*)&Ts[(16 * w + lm) * 72 + kt * 32 + lq * 8];
            #pragma unroll
            for (int nt = 0; nt < 4; ++nt) {
                bf16x8 b = *(const bf16x8*)&Vs[(nt * 16 + lm) * 72 + kt * 32 + lq * 8];
                a2[nt] = __builtin_amdgcn_mfma_f32_16x16x32_bf16(a, b, a2[nt], 0, 0, 0);
            }
        }
        #pragma unroll
        for (int kt = 0; kt < 4; ++kt) {
            bf16x8 a = *(const bf16x8*)&Ps[(16 * w + lm + 1) * 136 + kt * 32 + lq * 8];
            #pragma unroll
            for (int nt = 0; nt < 4; ++nt) {
                bf16x8 b = *(const bf16x8*)&Ss[(nt * 16 + lm) * 136 + kt * 32 + lq * 8];
                a2[nt] = __builtin_amdgcn_mfma_f32_16x16x32_bf16(a, b, a2[nt], 0, 0, 0);
            }
        }
        __syncthreads();   // RY readers done; safe to write ybuf
        #pragma unroll
        for (int nt = 0; nt < 4; ++nt) {
            const int chunk = nt * 16 + lm;
            float gg[4];
            #pragma unroll
            for (int r = 0; r < 4; ++r) {
                const int tt = 16 * w + lq * 4 + r;
                const float vv = bf2f(Vs[chunk * 72 + tt]);
                gg[r] = gelu_fast(fmaf(Dc, vv, a2[nt][r]));
            }
            const int p0 = 8 * w + 2 * lq;
            ybuf[chunk * 34 + p0]     = pack2(gg[0], gg[1]);
            ybuf[chunk * 34 + p0 + 1] = pack2(gg[2], gg[3]);
        }
        __syncthreads();
        // g'[bb][lt][c][l&127]:  u32 view, 64 u32 per (lt,c) row
        unsigned int* gp = (unsigned int*)gprime
                         + (size_t)bb * 32 * 1024 * 64 + (size_t)c * 64;
        #pragma unroll
        for (int q = 0; q < 8; ++q) {
            const int idx = q * 256 + t;               // 0..2047, l = 2*idx
            const int lt = idx >> 6, w32 = idx & 63;
            gp[(size_t)lt * (1024 * 64) + w32] = ybuf[(idx >> 5) * 34 + (idx & 31)];
        }
        __syncthreads();
    };

    // ---- pipeline ----
    deltascan(0);

    {   // P rows tt: (Re,-Im) of 2*Ct*lam^tt ; wave w covers [16w,16w+16) (+row 64 on w=3)
        c32 z = cmul((c32){c2r, -c2mi}, cpow16(lam, w));
        const int steps = (w == 3) ? 17 : 16;
        for (int s = 0; s < steps; ++s) {
            const int tt = 16 * w + s;
            *(unsigned int*)&Ps[tt * 136 + 2 * n] = pack2(z.x, -z.y);
            z = cmul(z, lam);
        }
    }
    {   // R rows u: (Re,Im) lam^-u  (overwrites F, dead post-Delta0)
        c32 z = cpow16(inv, w);
        #pragma unroll
        for (int s = 0; s < 16; ++s) {
            const int u = 16 * w + s;
            *(unsigned int*)&Rs[u * 136 + 2 * n] = pack2(z.x, z.y);
            z = cmul(z, inv);
        }
    }
    __syncthreads();
    {   // GEMM1: T = tril(P@R), M=N=64, K=128  (once per channel)
        floatx4 a1[4];
        #pragma unroll
        for (int nt = 0; nt < 4; ++nt) a1[nt] = (floatx4){0.f, 0.f, 0.f, 0.f};
        #pragma unroll
        for (int kt = 0; kt < 4; ++kt) {
            bf16x8 a = *(const bf16x8*)&Ps[(16 * w + lm) * 136 + kt * 32 + lq * 8];
            #pragma unroll
            for (int nt = 0; nt < 4; ++nt) {
                bf16x8 b = *(const bf16x8*)&Rs[(nt * 16 + lm) * 136 + kt * 32 + lq * 8];
                a1[nt] = __builtin_amdgcn_mfma_f32_16x16x32_bf16(a, b, a1[nt], 0, 0, 0);
            }
        }
        #pragma unroll
        for (int nt = 0; nt < 4; ++nt)
            #pragma unroll
            for (int r = 0; r < 4; ++r) {
                const int row = 16 * w + lq * 4 + r, col = nt * 16 + lm;
                Ts[row * 72 + col] = f2bf(row >= col ? a1[nt][r] : 0.f);
            }
    }
    __syncthreads();

    gemm2_epi(0);
    deltascan(1);
    gemm2_epi(1);
}

// ---------------------------------------------------------------------------
// W (k=1024, o=512) fp32 -> Wt (o=512, k=1024) bf16.
// ---------------------------------------------------------------------------
__global__ __launch_bounds__(256) void transpose_w_kernel(
    const float* __restrict__ W, unsigned short* __restrict__ Wt)
{
    __shared__ float tileF[64 * 65];
    const int t = threadIdx.x;
    const int o0 = blockIdx.x * 64, k0 = blockIdx.y * 64;
    {
        const int ty = t >> 6, tx = t & 63;
        #pragma unroll
        for (int r = 0; r < 16; ++r) {
            const int ki = r * 4 + ty;
            tileF[ki * 65 + tx] = W[(size_t)(k0 + ki) * OUTF + o0 + tx];
        }
    }
    __syncthreads();
    {
        const int ty = t >> 5, tx = t & 31;
        #pragma unroll
        for (int r = 0; r < 8; ++r) {
            const int oi = r * 8 + ty;
            unsigned int u0 = f2bf(tileF[(2 * tx) * 65 + oi]);
            unsigned int u1 = f2bf(tileF[(2 * tx + 1) * 65 + oi]);
            *(unsigned int*)&Wt[(size_t)(o0 + oi) * H_CH + k0 + 2 * tx] = u0 | (u1 << 16);
        }
    }
}

// ---------------------------------------------------------------------------
// GEMM: out[b,o,l] = sum_k Wt[o,k]*g'[b,lt,k,l'] + b_out[o].
// 64(o) x 128(l) tiles, BK=32, 512 blocks (2/CU), register prefetch,
// B staged straight from blocked g' with in-LDS transpose.
// ---------------------------------------------------------------------------
__global__ __launch_bounds__(256) void gemm_kernel(
    const unsigned short* __restrict__ gp, const unsigned short* __restrict__ Wt,
    const float* __restrict__ b_out, float* __restrict__ out)
{
    __shared__ unsigned short As[64 * 40];      // [o][k] rows padded to 80B
    __shared__ unsigned short Bs[128 * 40];     // [l][k]
    const int t = threadIdx.x, lane = t & 63, w = t >> 6;
    const int lm = lane & 15, lq = lane >> 4;
    const int bx = blockIdx.x;                  // l-tile 0..31
    const int o0 = blockIdx.y * 64;
    const int bb = blockIdx.z;
    const int l0 = bx * 128;
    const unsigned short* bsrc = gp + (size_t)(bb * 32 + bx) * (1024 * 128);

    const int arow = t >> 2, aq = t & 3;        // A staging role
    const int bp = t & 15, bgq = t >> 4;        // B staging: k-pair, l-octet

    uint4 areg, breg0, breg1;
    {
        areg  = *(const uint4*)(Wt + (size_t)(o0 + arow) * H_CH + aq * 8);
        const unsigned short* b0 = bsrc + (size_t)(2 * bp) * 128 + bgq * 8;
        breg0 = *(const uint4*)(b0);
        breg1 = *(const uint4*)(b0 + 128);
    }

    floatx4 acc[4][2];
    #pragma unroll
    for (int i = 0; i < 4; ++i)
        #pragma unroll
        for (int jj = 0; jj < 2; ++jj) acc[i][jj] = (floatx4){0.f, 0.f, 0.f, 0.f};

    for (int kt = 0; kt < 32; ++kt) {
        if (kt) __syncthreads();                // prev iter's LDS reads done
        *(uint4*)&As[arow * 40 + aq * 8] = areg;
        {   // transpose-scatter: Bs[l][k] u32 pairs (k=2bp, 2bp+1)
            unsigned int* bu = (unsigned int*)Bs;
            const unsigned int* a = (const unsigned int*)&breg0;
            const unsigned int* b = (const unsigned int*)&breg1;
            #pragma unroll
            for (int i = 0; i < 4; ++i) {
                unsigned int lo = (a[i] & 0xffffu) | (b[i] << 16);
                unsigned int hi = (a[i] >> 16) | (b[i] & 0xffff0000u);
                bu[(bgq * 8 + 2 * i) * 20 + bp]     = lo;
                bu[(bgq * 8 + 2 * i + 1) * 20 + bp] = hi;
            }
        }
        __syncthreads();
        if (kt < 31) {                          // prefetch next k-tile
            const int k0 = (kt + 1) * 32;
            areg  = *(const uint4*)(Wt + (size_t)(o0 + arow) * H_CH + k0 + aq * 8);
            const unsigned short* b0 = bsrc + (size_t)(k0 + 2 * bp) * 128 + bgq * 8;
            breg0 = *(const uint4*)(b0);
            breg1 = *(const uint4*)(b0 + 128);
        }

        bf16x8 af[4], bfr[2];
        #pragma unroll
        for (int sm = 0; sm < 4; ++sm)
            af[sm] = *(const bf16x8*)&As[(sm * 16 + lm) * 40 + lq * 8];
        #pragma unroll
        for (int sn = 0; sn < 2; ++sn)
            bfr[sn] = *(const bf16x8*)&Bs[(w * 32 + sn * 16 + lm) * 40 + lq * 8];
        #pragma unroll
        for (int sm = 0; sm < 4; ++sm)
            #pragma unroll
            for (int sn = 0; sn < 2; ++sn)
                acc[sm][sn] = __builtin_amdgcn_mfma_f32_16x16x32_bf16(
                    af[sm], bfr[sn], acc[sm][sn], 0, 0, 0);
    }

    #pragma unroll
    for (int sm = 0; sm < 4; ++sm)
        #pragma unroll
        for (int sn = 0; sn < 2; ++sn)
            #pragma unroll
            for (int r = 0; r < 4; ++r) {
                const int o = o0 + sm * 16 + lq * 4 + r;
                const int l = l0 + w * 32 + sn * 16 + lm;
                out[((size_t)bb * OUTF + o) * LSEQ + l] = acc[sm][sn][r] + b_out[o];
            }
}

// ---------------------------------------------------------------------------
extern "C" void kernel_launch(void* const* d_in, const int* in_sizes, int n_in,
                              void* d_out, int out_size, void* d_ws, size_t ws_size,
                              hipStream_t stream) {
    const float* x      = (const float*)d_in[0];
    const float* log_dt = (const float*)d_in[1];
    const float* A_re   = (const float*)d_in[2];
    const float* A_im   = (const float*)d_in[3];
    const float* C_re   = (const float*)d_in[4];
    const float* C_im   = (const float*)d_in[5];
    const float* Dp     = (const float*)d_in[6];
    const float* W_out  = (const float*)d_in[7];
    const float* b_out  = (const float*)d_in[8];
    float* out = (float*)d_out;

    // Workspace: g' [0,16M), Wt [17M,18M), coef [19M,21M)
    char* ws = (char*)d_ws;
    unsigned short* gprime = (unsigned short*)ws;
    unsigned short* Wt     = (unsigned short*)(ws + (size_t)17 * 1024 * 1024);
    float*          coef   = (float*)(ws + (size_t)19 * 1024 * 1024);

    coef_kernel<<<256, 256, 0, stream>>>(log_dt, A_re, A_im, C_re, C_im, coef);
    s4_fused_kernel<<<1024, 256, 0, stream>>>(x, coef, Dp, gprime);
    transpose_w_kernel<<<dim3(8, 16), 256, 0, stream>>>(W_out, Wt);
    gemm_kernel<<<dim3(32, 8, 2), 256, 0, stream>>>(gprime, Wt, b_out, out);
}